// Round 8
// baseline (478.123 us; speedup 1.0000x reference)
//
#include <hip/hip_runtime.h>
#include <math.h>

#define F 1024
#define NROWS 8192
#define NELEM (NROWS * F)

typedef unsigned short ushort_t;
typedef short bf16x8 __attribute__((ext_vector_type(8)));
typedef float f32x4 __attribute__((ext_vector_type(4)));
typedef unsigned short ushort8 __attribute__((ext_vector_type(8)));

__device__ __forceinline__ ushort_t f2bf(float f) {
  unsigned u = __float_as_uint(f);
  unsigned r = (u + 0x7fffu + ((u >> 16) & 1u)) >> 16;
  return (ushort_t)r;
}
__device__ __forceinline__ float bf2f(ushort_t b) {
  return __uint_as_float(((unsigned)b) << 16);
}

typedef const __attribute__((address_space(1))) unsigned int* gas_ptr;
typedef __attribute__((address_space(3))) unsigned int* las_ptr;
__device__ __forceinline__ void gload16(const void* g, const void* l) {
  __builtin_amdgcn_global_load_lds((gas_ptr)(unsigned long long)g,
                                   (las_ptr)(unsigned int)(unsigned long long)l,
                                   16, 0, 0);
}

// ---------------- tconv + fused sumsq ----------------
__global__ __launch_bounds__(256) void tconv_kernel(const float* __restrict__ x,
                                                    ushort_t* __restrict__ xthi,
                                                    ushort_t* __restrict__ xtlo,
                                                    float* __restrict__ partial) {
    __shared__ ushort_t th[64][68];
    __shared__ ushort_t tl[64][68];
    __shared__ float sdata[256];
    int c0 = blockIdx.x * 64;
    int r0 = blockIdx.y * 64;
    int tid = threadIdx.x;
    float ss = 0.f;
#pragma unroll
    for (int i = 0; i < 4; ++i) {
        int q = tid + 256 * i;
        int r = q >> 4;
        int cq = (q & 15) << 2;
        float4 vx = *(const float4*)&x[(size_t)(r0 + r) * 1024 + c0 + cq];
        float vv[4] = {vx.x, vx.y, vx.z, vx.w};
#pragma unroll
        for (int j = 0; j < 4; ++j) {
            ss = fmaf(vv[j], vv[j], ss);
            ushort_t h = f2bf(vv[j]);
            ushort_t l = f2bf(vv[j] - bf2f(h));
            th[r][cq + j] = h;
            tl[r][cq + j] = l;
        }
    }
    sdata[tid] = ss;
    __syncthreads();
    for (int off = 128; off > 0; off >>= 1) {
        if (tid < off) sdata[tid] += sdata[tid + off];
        __syncthreads();
    }
    if (tid == 0) partial[blockIdx.y * 16 + blockIdx.x] = sdata[0];
#pragma unroll
    for (int i = 0; i < 2; ++i) {
        int q = tid + 256 * i;
        int c = q >> 3;
        int rq = (q & 7) << 3;
        ushort8 oh, ol;
#pragma unroll
        for (int j = 0; j < 8; ++j) {
            oh[j] = th[rq + j][c];
            ol[j] = tl[rq + j][c];
        }
        *(ushort8*)&xthi[(size_t)(c0 + c) * 8192 + r0 + rq] = oh;
        *(ushort8*)&xtlo[(size_t)(c0 + c) * 8192 + r0 + rq] = ol;
    }
}

// ---------------- SYRK 256x256: 10 triangle tiles, full NZ=16 / diag NZ=8, 1024 thr ----------------
__device__ __forceinline__ void stage256(const ushort_t* __restrict__ gp, int row0, int kk,
                                         ushort_t* sbase, int tid) {
    int r = tid >> 2, pos = tid & 3;
    int kc = (pos ^ ((r >> 1) & 3)) << 3;
    gload16(gp + (size_t)(row0 + r) * 8192 + kk + kc, sbase + ((tid >> 6) << 9));
}

__global__ __launch_bounds__(1024, 1) void syrk256_kernel(
    const ushort_t* __restrict__ XThi, const ushort_t* __restrict__ XTlo,
    float* __restrict__ P)
{
    __shared__ ushort_t smem[65536];   // 128 KB
    int id = blockIdx.x;
    int tid = threadIdx.x, lane = tid & 63, w = tid >> 6;
    int wm = w >> 2, wn = w & 3;       // 4x4 wave grid, 64x64 per wave
    int lr = lane & 15, cg = lane >> 4;

    bool isfull = id < 96;
    int bi, bj, z, k0, sliceBase;
    if (isfull) {
        int f = id >> 4;
        z = id & 15;
        bi = 1;
        while (bi * (bi + 1) / 2 <= f) ++bi;
        bj = f - bi * (bi - 1) / 2;
        k0 = z << 9;                   // K-chunk 512
        sliceBase = (f << 4) + z;
    } else {
        int d = (id - 96) >> 3;
        z = (id - 96) & 7;
        bi = d; bj = d;
        k0 = z << 10;                  // K-chunk 1024
        sliceBase = 96 + (d << 3) + z;
    }
    int arow0 = bi << 8, brow0 = bj << 8;

    f32x4 zero4 = {0.f, 0.f, 0.f, 0.f};
    f32x4 acc[4][4];
#pragma unroll
    for (int a = 0; a < 4; ++a)
#pragma unroll
        for (int b = 0; b < 4; ++b) acc[a][b] = zero4;

#define S2_STAGE_F(BUF, KT)                                                        \
    {                                                                              \
        ushort_t* sb = smem + (BUF) * 32768;                                       \
        int kk = k0 + ((KT) << 5);                                                 \
        stage256(XThi, arow0, kk, sb + 0, tid);                                    \
        stage256(XTlo, arow0, kk, sb + 8192, tid);                                 \
        stage256(XThi, brow0, kk, sb + 16384, tid);                                \
        stage256(XTlo, brow0, kk, sb + 24576, tid);                                \
    }

#define S2_STAGE_D(BUF, KT)                                                        \
    {                                                                              \
        ushort_t* sb = smem + (BUF) * 16384;                                       \
        int kk = k0 + ((KT) << 5);                                                 \
        stage256(XThi, arow0, kk, sb + 0, tid);                                    \
        stage256(XTlo, arow0, kk, sb + 8192, tid);                                 \
    }

#define S2_COMP(SB, BH, BL)                                                        \
    {                                                                              \
        const ushort_t* sb = (SB);                                                 \
        int xo = (cg ^ ((lr >> 1) & 3)) << 3;                                      \
        bf16x8 ah[4], al[4], bh[4], bl[4];                                         \
        _Pragma("unroll")                                                          \
        for (int fx = 0; fx < 4; ++fx) {                                           \
            int ao = ((wm << 6) + (fx << 4) + lr) * 32 + xo;                       \
            int bo = ((wn << 6) + (fx << 4) + lr) * 32 + xo;                       \
            ah[fx] = *(const bf16x8*)&sb[0 + ao];                                  \
            al[fx] = *(const bf16x8*)&sb[8192 + ao];                               \
            bh[fx] = *(const bf16x8*)&sb[(BH) + bo];                               \
            bl[fx] = *(const bf16x8*)&sb[(BL) + bo];                               \
        }                                                                          \
        _Pragma("unroll")                                                          \
        for (int fm = 0; fm < 4; ++fm)                                             \
            _Pragma("unroll")                                                      \
            for (int fn = 0; fn < 4; ++fn) {                                       \
                acc[fm][fn] = __builtin_amdgcn_mfma_f32_16x16x32_bf16(             \
                    ah[fm], bh[fn], acc[fm][fn], 0, 0, 0);                         \
                acc[fm][fn] = __builtin_amdgcn_mfma_f32_16x16x32_bf16(             \
                    ah[fm], bl[fn], acc[fm][fn], 0, 0, 0);                         \
                acc[fm][fn] = __builtin_amdgcn_mfma_f32_16x16x32_bf16(             \
                    al[fm], bh[fn], acc[fm][fn], 0, 0, 0);                         \
            }                                                                      \
    }

    if (isfull) {
        S2_STAGE_F(0, 0)
        for (int kt = 0; kt < 15; ++kt) {
            if ((kt & 1) == 0) S2_STAGE_F(1, kt + 1) else S2_STAGE_F(0, kt + 1)
            asm volatile("s_waitcnt vmcnt(4)" ::: "memory");
            __builtin_amdgcn_s_barrier();
            __builtin_amdgcn_sched_barrier(0);
            if ((kt & 1) == 0) S2_COMP(smem + 0, 16384, 24576)
            else               S2_COMP(smem + 32768, 16384, 24576)
            __builtin_amdgcn_sched_barrier(0);
            __builtin_amdgcn_s_barrier();
        }
        asm volatile("s_waitcnt vmcnt(0)" ::: "memory");
        __builtin_amdgcn_s_barrier();
        __builtin_amdgcn_sched_barrier(0);
        S2_COMP(smem + 32768, 16384, 24576)   // kt=15 -> slot 1
    } else {
        S2_STAGE_D(0, 0)
        for (int kt = 0; kt < 31; ++kt) {
            if ((kt & 1) == 0) S2_STAGE_D(1, kt + 1) else S2_STAGE_D(0, kt + 1)
            asm volatile("s_waitcnt vmcnt(2)" ::: "memory");
            __builtin_amdgcn_s_barrier();
            __builtin_amdgcn_sched_barrier(0);
            if ((kt & 1) == 0) S2_COMP(smem + 0, 0, 8192)
            else               S2_COMP(smem + 16384, 0, 8192)
            __builtin_amdgcn_sched_barrier(0);
            __builtin_amdgcn_s_barrier();
        }
        asm volatile("s_waitcnt vmcnt(0)" ::: "memory");
        __builtin_amdgcn_s_barrier();
        __builtin_amdgcn_sched_barrier(0);
        S2_COMP(smem + 16384, 0, 8192)        // kt=31 -> slot 1
    }

    float* Pt = P + ((size_t)sliceBase << 16);
#pragma unroll
    for (int fm = 0; fm < 4; ++fm)
#pragma unroll
        for (int fn = 0; fn < 4; ++fn)
#pragma unroll
            for (int rr = 0; rr < 4; ++rr) {
                int row = (wm << 6) + (fm << 4) + (cg << 2) + rr;
                int col = (wn << 6) + (fn << 4) + lr;
                Pt[row * 256 + col] = acc[fm][fn][rr];
            }
}

// ---------------- reduceH: fused damp + z-sum (16 full / 8 diag) + split + mirror ----------------
__global__ void reduceH_kernel(const float* __restrict__ P, const float* __restrict__ part,
                               ushort_t* __restrict__ Hhi, ushort_t* __restrict__ Hlo) {
    __shared__ float red[256];
    int tid = threadIdx.x;
    float s0 = 0.f;
    for (int i = tid; i < 2048; i += 256) s0 += part[i];
    red[tid] = s0;
    __syncthreads();
    for (int off = 128; off > 0; off >>= 1) {
        if (tid < off) red[tid] += red[tid + off];
        __syncthreads();
    }
    float damp = 0.01f * (red[0] / (float)NELEM);

    int b = blockIdx.x;                 // 640 blocks
    int tile = b >> 6;                  // 0..9
    int li = ((b & 63) << 10) + (tid << 2);
    int bi, bj, base, nz;
    if (tile < 6) {
        int f = tile;
        bi = 1;
        while (bi * (bi + 1) / 2 <= f) ++bi;
        bj = f - bi * (bi - 1) / 2;
        base = f << 4;  nz = 16;
    } else {
        int d = tile - 6;
        bi = d; bj = d;
        base = 96 + (d << 3);  nz = 8;
    }
    const float* Pt = P + ((size_t)base << 16);
    float sx = 0.f, sy = 0.f, sz = 0.f, sw = 0.f;
    for (int zz = 0; zz < nz; ++zz) {
        float4 p4 = *(const float4*)&Pt[((size_t)zz << 16) + li];
        sx += p4.x; sy += p4.y; sz += p4.z; sw += p4.w;
    }
    int r = li >> 8, c = li & 255;
    int gi = (bi << 8) + r;
    float v4[4] = {sx, sy, sz, sw};
#pragma unroll
    for (int k = 0; k < 4; ++k) {
        int gj = (bj << 8) + c + k;
        float val = v4[k];
        if (gi == gj) val += damp;
        ushort_t h = f2bf(val), l = f2bf(val - bf2f(h));
        Hhi[gi * F + gj] = h;
        Hlo[gi * F + gj] = l;
        if (bi != bj) {
            Hhi[gj * F + gi] = h;
            Hlo[gj * F + gi] = l;
        }
    }
}

// ---------------- single matvec: y = H * ones (bf16 H) ----------------
__global__ void matvec_bf16_kernel(const ushort_t* __restrict__ Hhi, const float* __restrict__ v,
                                   float* __restrict__ y, int first) {
    __shared__ float sdata[256];
    int row = blockIdx.x, tid = threadIdx.x;
    float s = 0.f;
    if (first) {
        for (int j = tid; j < F; j += 256) s += bf2f(Hhi[row * F + j]);
    } else {
        for (int j = tid; j < F; j += 256) s = fmaf(bf2f(Hhi[row * F + j]), v[j], s);
    }
    sdata[tid] = s;
    __syncthreads();
    for (int off = 128; off > 0; off >>= 1) {
        if (tid < off) sdata[tid] += sdata[tid + off];
        __syncthreads();
    }
    if (tid == 0) y[row] = sdata[0];
}

// ---------------- initX1: lam = ||y||/32, c = 1/(1.15 lam), X1 = 2cI - c^2 H ----------------
__global__ void initX1_kernel(const ushort_t* __restrict__ Hhi, const ushort_t* __restrict__ Hlo,
                              ushort_t* __restrict__ Xhi, ushort_t* __restrict__ Xlo,
                              const float* __restrict__ y, float* __restrict__ scal) {
    __shared__ float red[256];
    int tid = threadIdx.x;
    float4 a = ((const float4*)y)[tid];
    float s = a.x * a.x + a.y * a.y + a.z * a.z + a.w * a.w;
    red[tid] = s;
    __syncthreads();
    for (int off = 128; off > 0; off >>= 1) {
        if (tid < off) red[tid] += red[tid + off];
        __syncthreads();
    }
    float lam = sqrtf(red[0]) * (1.0f / 32.0f);
    float c = 1.0f / (1.15f * lam);
    if (blockIdx.x == 0 && tid == 0) { scal[2] = lam; scal[3] = c; }
    float c2 = c * c;
    int idx0 = (blockIdx.x * 256 + tid) * 4;
#pragma unroll
    for (int k = 0; k < 4; ++k) {
        int idx = idx0 + k;
        float hv = bf2f(Hhi[idx]) + bf2f(Hlo[idx]);
        float val = -c2 * hv + (((idx >> 10) == (idx & 1023)) ? 2.f * c : 0.f);
        ushort_t h = f2bf(val);
        Xhi[idx] = h;
        Xlo[idx] = f2bf(val - bf2f(h));
    }
}

// ---------------- NS GEMM: 64x64 tile, K=1024, ring-4 prefetch-2 (measured body) ----------------
__device__ __forceinline__ void stage64(const ushort_t* __restrict__ gp, int row0, int kk,
                                        ushort_t* sbase, int tid) {
    int r = tid >> 2, pos = tid & 3;
    int kc = (pos ^ ((r >> 1) & 3)) << 3;
    gload16(gp + (size_t)(row0 + r) * 1024 + kk + kc, sbase + (size_t)(tid >> 6 << 9));
}

template <int TERMS, int MODE>
__global__ __launch_bounds__(256) void ns_gemm_kernel(
    const ushort_t* __restrict__ Ahi, const ushort_t* __restrict__ Alo,
    const ushort_t* __restrict__ Bhi, const ushort_t* __restrict__ Blo,
    const ushort_t* __restrict__ Xchi, const ushort_t* __restrict__ Xclo,
    ushort_t* __restrict__ Ohi, ushort_t* __restrict__ Olo,
    float* __restrict__ Of)
{
    constexpr int SLOT = (TERMS == 3) ? 8192 : 4096;
    __shared__ ushort_t smem[4 * SLOT];
    int tid = threadIdx.x, lane = tid & 63, w = tid >> 6;
    int wm = w >> 1, wn = w & 1;
    int row0 = blockIdx.y * 64, col0 = blockIdx.x * 64;
    int lr = lane & 15, cg = lane >> 4;

    f32x4 zero4 = {0.f, 0.f, 0.f, 0.f};
    f32x4 acc[2][2];
#pragma unroll
    for (int a = 0; a < 2; ++a)
#pragma unroll
        for (int b = 0; b < 2; ++b) acc[a][b] = zero4;

#define NS_STAGE(KT)                                                               \
    {                                                                              \
        ushort_t* sb = smem + (size_t)((KT) & 3) * SLOT;                           \
        int kk = (KT) << 5;                                                        \
        stage64(Ahi, row0, kk, sb + 0, tid);                                       \
        stage64(Bhi, col0, kk, sb + 2048, tid);                                    \
        if constexpr (TERMS == 3) {                                                \
            stage64(Alo, row0, kk, sb + 4096, tid);                                \
            stage64(Blo, col0, kk, sb + 6144, tid);                                \
        }                                                                          \
    }

#define NS_COMPUTE(KT)                                                             \
    {                                                                              \
        const ushort_t* sb = smem + (size_t)((KT) & 3) * SLOT;                     \
        bf16x8 ah[2], bh[2], al[2], bl[2];                                         \
        _Pragma("unroll")                                                          \
        for (int fx = 0; fx < 2; ++fx) {                                           \
            int xo = (cg ^ ((lr >> 1) & 3)) << 3;                                  \
            int ao = ((wm << 5) + (fx << 4) + lr) * 32 + xo;                       \
            int bo = ((wn << 5) + (fx << 4) + lr) * 32 + xo;                       \
            ah[fx] = *(const bf16x8*)&sb[0 + ao];                                  \
            bh[fx] = *(const bf16x8*)&sb[2048 + bo];                               \
            if constexpr (TERMS == 3) {                                            \
                al[fx] = *(const bf16x8*)&sb[4096 + ao];                           \
                bl[fx] = *(const bf16x8*)&sb[6144 + bo];                           \
            }                                                                      \
        }                                                                          \
        _Pragma("unroll")                                                          \
        for (int fm = 0; fm < 2; ++fm)                                             \
            _Pragma("unroll")                                                      \
            for (int fn = 0; fn < 2; ++fn) {                                       \
                acc[fm][fn] = __builtin_amdgcn_mfma_f32_16x16x32_bf16(             \
                    ah[fm], bh[fn], acc[fm][fn], 0, 0, 0);                         \
                if constexpr (TERMS == 3) {                                        \
                    acc[fm][fn] = __builtin_amdgcn_mfma_f32_16x16x32_bf16(         \
                        ah[fm], bl[fn], acc[fm][fn], 0, 0, 0);                     \
                    acc[fm][fn] = __builtin_amdgcn_mfma_f32_16x16x32_bf16(         \
                        al[fm], bh[fn], acc[fm][fn], 0, 0, 0);                     \
                }                                                                  \
            }                                                                      \
    }

    NS_STAGE(0)
    NS_STAGE(1)
    for (int kt = 0; kt < 30; ++kt) {
        NS_STAGE(kt + 2)
        if constexpr (TERMS == 3) { asm volatile("s_waitcnt vmcnt(8)" ::: "memory"); }
        else                      { asm volatile("s_waitcnt vmcnt(4)" ::: "memory"); }
        __builtin_amdgcn_s_barrier();
        __builtin_amdgcn_sched_barrier(0);
        NS_COMPUTE(kt)
        __builtin_amdgcn_sched_barrier(0);
    }
    if constexpr (TERMS == 3) { asm volatile("s_waitcnt vmcnt(4)" ::: "memory"); }
    else                      { asm volatile("s_waitcnt vmcnt(2)" ::: "memory"); }
    __builtin_amdgcn_s_barrier();
    __builtin_amdgcn_sched_barrier(0);
    NS_COMPUTE(30)
    asm volatile("s_waitcnt vmcnt(0)" ::: "memory");
    __builtin_amdgcn_s_barrier();
    __builtin_amdgcn_sched_barrier(0);
    NS_COMPUTE(31)

#pragma unroll
    for (int fm = 0; fm < 2; ++fm)
#pragma unroll
        for (int fn = 0; fn < 2; ++fn)
#pragma unroll
            for (int rr = 0; rr < 4; ++rr) {
                int r = row0 + (wm << 5) + fm * 16 + cg * 4 + rr;
                int c = col0 + (wn << 5) + fn * 16 + lr;
                size_t idx = (size_t)r * F + c;
                float val = acc[fm][fn][rr];
                if constexpr (MODE == 0) {
                    ushort_t h = f2bf(val);
                    Ohi[idx] = h;
                    Olo[idx] = f2bf(val - bf2f(h));
                } else {
                    float xc = bf2f(Xchi[idx]) + bf2f(Xclo[idx]);
                    val = 2.0f * xc - val;
                    if constexpr (MODE == 1) {
                        ushort_t h = f2bf(val);
                        Ohi[idx] = h;
                        Olo[idx] = f2bf(val - bf2f(h));
                    } else {
                        Of[idx] = val;
                    }
                }
            }
    if constexpr (MODE == 2) {
        if (blockIdx.x == 0 && blockIdx.y == 0) {
            int i0 = tid * 4;
#pragma unroll
            for (int k = 0; k < 4; ++k)
                Of[(size_t)F * F + i0 + k] = (float)(i0 + k);
        }
    }
}

// ======================= fp32 ultra-fallback =======================
__global__ void sumsq_partial_kernel(const float* __restrict__ x, float* __restrict__ partial) {
    __shared__ float sdata[256];
    int tid = threadIdx.x;
    int base = blockIdx.x * 4096;
    float s = 0.f;
    for (int i = tid; i < 4096; i += 256) {
        float v = x[base + i];
        s = fmaf(v, v, s);
    }
    sdata[tid] = s;
    __syncthreads();
    for (int off = 128; off > 0; off >>= 1) {
        if (tid < off) sdata[tid] += sdata[tid + off];
        __syncthreads();
    }
    if (tid == 0) partial[blockIdx.x] = sdata[0];
}

__global__ void finish_damp_kernel(const float* __restrict__ partial, float* __restrict__ scal) {
    __shared__ float sdata[256];
    int tid = threadIdx.x;
    float s = 0.f;
    for (int i = tid; i < 2048; i += 256) s += partial[i];
    sdata[tid] = s;
    __syncthreads();
    for (int off = 128; off > 0; off >>= 1) {
        if (tid < off) sdata[tid] += sdata[tid + off];
        __syncthreads();
    }
    if (tid == 0) {
        float mean = sdata[0] / (float)NELEM;
        scal[1] = 0.01f * mean;
    }
}

__global__ void init_v_kernel(float* __restrict__ v) {
    int i = blockIdx.x * 256 + threadIdx.x;
    if (i < F) v[i] = 1.0f;
}

__global__ void matvec_kernel(const float* __restrict__ H, const float* __restrict__ v,
                              float* __restrict__ y) {
    __shared__ float sdata[256];
    int row = blockIdx.x, tid = threadIdx.x;
    float s = 0.f;
    for (int j = tid; j < F; j += 256) s = fmaf(H[row * F + j], v[j], s);
    sdata[tid] = s;
    __syncthreads();
    for (int off = 128; off > 0; off >>= 1) {
        if (tid < off) sdata[tid] += sdata[tid + off];
        __syncthreads();
    }
    if (tid == 0) y[row] = sdata[0];
}

__global__ void normalize_kernel(const float* __restrict__ y, float* __restrict__ v,
                                 float* __restrict__ scal) {
    __shared__ float sdata[256];
    __shared__ float lam;
    int tid = threadIdx.x;
    float s = 0.f;
    for (int i = tid; i < F; i += 256) {
        float t = y[i];
        s = fmaf(t, t, s);
    }
    sdata[tid] = s;
    __syncthreads();
    for (int off = 128; off > 0; off >>= 1) {
        if (tid < off) sdata[tid] += sdata[tid + off];
        __syncthreads();
    }
    if (tid == 0) {
        lam = sqrtf(sdata[0]);
        scal[2] = lam;
        scal[3] = 1.0f / (1.05f * lam);
    }
    __syncthreads();
    float il = 1.0f / lam;
    for (int i = tid; i < F; i += 256) v[i] = y[i] * il;
}

__global__ __launch_bounds__(256) void syrk_kernel(const float* __restrict__ X,
                                                   float* __restrict__ H,
                                                   const float* __restrict__ scal) {
    __shared__ float LA[16][64];
    __shared__ float LB[16][64];
    int tx = threadIdx.x, ty = threadIdx.y;
    int t = ty * 16 + tx;
    int i0 = blockIdx.y * 64, j0 = blockIdx.x * 64;
    int lk = t >> 4;
    int lc = (t & 15) << 2;
    float acc[4][4] = {};
    for (int k0 = 0; k0 < NROWS; k0 += 16) {
        int r = (k0 + lk) * F;
        float4 a4 = *(const float4*)&X[r + i0 + lc];
        float4 b4 = *(const float4*)&X[r + j0 + lc];
        __syncthreads();
        *(float4*)&LA[lk][lc] = a4;
        *(float4*)&LB[lk][lc] = b4;
        __syncthreads();
#pragma unroll
        for (int kk = 0; kk < 16; ++kk) {
            float4 a = *(const float4*)&LA[kk][ty << 2];
            float4 b = *(const float4*)&LB[kk][tx << 2];
            float av[4] = {a.x, a.y, a.z, a.w};
            float bv[4] = {b.x, b.y, b.z, b.w};
#pragma unroll
            for (int rr = 0; rr < 4; ++rr)
#pragma unroll
                for (int cc = 0; cc < 4; ++cc)
                    acc[rr][cc] = fmaf(av[rr], bv[cc], acc[rr][cc]);
        }
    }
    float damp = scal[1];
#pragma unroll
    for (int rr = 0; rr < 4; ++rr) {
        int i = i0 + (ty << 2) + rr;
#pragma unroll
        for (int cc = 0; cc < 4; ++cc) {
            int j = j0 + (tx << 2) + cc;
            float v = acc[rr][cc];
            if (i == j) v += damp;
            H[i * F + j] = v;
        }
    }
}

__global__ void init_X_kernel(float* __restrict__ A, const float* __restrict__ scal) {
    int idx = blockIdx.x * 256 + threadIdx.x;
    int i = idx >> 10, j = idx & (F - 1);
    A[idx] = (i == j) ? scal[3] : 0.0f;
}

__global__ __launch_bounds__(256) void gemm_nn_kernel(const float* __restrict__ A,
                                                      const float* __restrict__ Bm,
                                                      float* __restrict__ C,
                                                      const float* __restrict__ D,
                                                      int mode) {
    __shared__ float LA[16][64];
    __shared__ float LB[16][64];
    int tx = threadIdx.x, ty = threadIdx.y;
    int t = ty * 16 + tx;
    int i0 = blockIdx.y * 64, j0 = blockIdx.x * 64;
    int aii = t >> 2;
    int akq = (t & 3) << 2;
    int bkk = t >> 4;
    int bjq = (t & 15) << 2;
    float acc[4][4] = {};
    for (int k0 = 0; k0 < F; k0 += 16) {
        float4 a4 = *(const float4*)&A[(i0 + aii) * F + k0 + akq];
        float4 b4 = *(const float4*)&Bm[(k0 + bkk) * F + j0 + bjq];
        __syncthreads();
        LA[akq + 0][aii] = a4.x;
        LA[akq + 1][aii] = a4.y;
        LA[akq + 2][aii] = a4.z;
        LA[akq + 3][aii] = a4.w;
        *(float4*)&LB[bkk][bjq] = b4;
        __syncthreads();
#pragma unroll
        for (int kk = 0; kk < 16; ++kk) {
            float4 a = *(const float4*)&LA[kk][ty << 2];
            float4 b = *(const float4*)&LB[kk][tx << 2];
            float av[4] = {a.x, a.y, a.z, a.w};
            float bv[4] = {b.x, b.y, b.z, b.w};
#pragma unroll
            for (int rr = 0; rr < 4; ++rr)
#pragma unroll
                for (int cc = 0; cc < 4; ++cc)
                    acc[rr][cc] = fmaf(av[rr], bv[cc], acc[rr][cc]);
        }
    }
#pragma unroll
    for (int rr = 0; rr < 4; ++rr) {
        int i = i0 + (ty << 2) + rr;
#pragma unroll
        for (int cc = 0; cc < 4; ++cc) {
            int j = j0 + (tx << 2) + cc;
            float v = acc[rr][cc];
            if (mode == 1) v = 2.0f * D[i * F + j] - v;
            C[i * F + j] = v;
        }
    }
}

__global__ void finalize_kernel(const float* __restrict__ A, float* __restrict__ out) {
    int idx = blockIdx.x * 256 + threadIdx.x;
    if (idx < F * F) out[idx] = A[idx];
    else if (idx < F * F + F) out[idx] = (float)(idx - F * F);
}

// ======================= launch =======================
extern "C" void kernel_launch(void* const* d_in, const int* in_sizes, int n_in,
                              void* d_out, int out_size, void* d_ws, size_t ws_size,
                              hipStream_t stream) {
    const float* x = (const float*)d_in[0];
    float* out = (float*)d_out;

    char* base = (char*)d_ws;
    size_t off = 0;
    auto alloc = [&](size_t bytes) -> char* {
        char* p = base + off;
        off += bytes;
        off = (off + 255) & ~(size_t)255;
        return p;
    };
    float*    scal = (float*)alloc(64 * 4);
    float*    part = (float*)alloc(2048 * 4);
    ushort_t* XThi = (ushort_t*)alloc((size_t)NELEM * 2);
    ushort_t* XTlo = (ushort_t*)alloc((size_t)NELEM * 2);
    ushort_t* Hhi  = (ushort_t*)alloc((size_t)F * F * 2);
    ushort_t* Hlo  = (ushort_t*)alloc((size_t)F * F * 2);
    ushort_t* X0hi = (ushort_t*)alloc((size_t)F * F * 2);
    ushort_t* X0lo = (ushort_t*)alloc((size_t)F * F * 2);
    ushort_t* X1hi = (ushort_t*)alloc((size_t)F * F * 2);
    ushort_t* X1lo = (ushort_t*)alloc((size_t)F * F * 2);
    ushort_t* Shi  = (ushort_t*)alloc((size_t)F * F * 2);
    ushort_t* Slo  = (ushort_t*)alloc((size_t)F * F * 2);
    float*    v    = (float*)alloc(F * 4);
    float*    y    = (float*)alloc(F * 4);
    float*    P    = (float*)alloc((size_t)128 * 65536 * 4);   // 32 MB
    size_t need = off;

    if (ws_size >= need) {
        // ======== MFMA path ========
        tconv_kernel<<<dim3(16, 128), 256, 0, stream>>>(x, XThi, XTlo, part);

        syrk256_kernel<<<128, 1024, 0, stream>>>(XThi, XTlo, P);
        reduceH_kernel<<<640, 256, 0, stream>>>(P, part, Hhi, Hlo);

        matvec_bf16_kernel<<<F, 256, 0, stream>>>(Hhi, v, y, 1);
        initX1_kernel<<<1024, 256, 0, stream>>>(Hhi, Hlo, X0hi, X0lo, y, scal);

        ushort_t* xch = X0hi; ushort_t* xcl = X0lo;
        ushort_t* xnh = X1hi; ushort_t* xnl = X1lo;
        dim3 g(16, 16);
        for (int it = 0; it < 4; ++it) {
            bool last = (it == 3);
            if (it < 1) {
                ns_gemm_kernel<1, 0><<<g, 256, 0, stream>>>(xch, xcl, Hhi, Hlo,
                                                            nullptr, nullptr, Shi, Slo, nullptr);
                ns_gemm_kernel<1, 1><<<g, 256, 0, stream>>>(Shi, Slo, xch, xcl,
                                                            xch, xcl, xnh, xnl, nullptr);
            } else {
                ns_gemm_kernel<3, 0><<<g, 256, 0, stream>>>(xch, xcl, Hhi, Hlo,
                                                            nullptr, nullptr, Shi, Slo, nullptr);
                if (last)
                    ns_gemm_kernel<3, 2><<<g, 256, 0, stream>>>(Shi, Slo, xch, xcl,
                                                                xch, xcl, nullptr, nullptr, out);
                else
                    ns_gemm_kernel<3, 1><<<g, 256, 0, stream>>>(Shi, Slo, xch, xcl,
                                                                xch, xcl, xnh, xnl, nullptr);
            }
            ushort_t* th = xch; xch = xnh; xnh = th;
            ushort_t* tl = xcl; xcl = xnl; xnl = tl;
        }
    } else {
        // -------- fp32 ultra-fallback --------
        float* ws = (float*)d_ws;
        float* fscal    = ws;
        float* fpartial = ws + 64;
        float* fH  = ws + 4096;
        float* fA  = fH + F * F;
        float* fB  = fA + F * F;
        float* fv  = fB + F * F;
        float* fy  = fv + F;
        float* R = out;

        sumsq_partial_kernel<<<2048, 256, 0, stream>>>(x, fpartial);
        finish_damp_kernel<<<1, 256, 0, stream>>>(fpartial, fscal);

        dim3 grid16(16, 16), blk16(16, 16);
        syrk_kernel<<<grid16, blk16, 0, stream>>>(x, fH, fscal);

        init_v_kernel<<<4, 256, 0, stream>>>(fv);
        for (int it = 0; it < 12; ++it) {
            matvec_kernel<<<F, 256, 0, stream>>>(fH, fv, fy);
            normalize_kernel<<<1, 256, 0, stream>>>(fy, fv, fscal);
        }

        init_X_kernel<<<(F * F) / 256, 256, 0, stream>>>(fA, fscal);
        float* Xc = fA;
        float* Xn = fB;
        for (int it = 0; it < 8; ++it) {
            gemm_nn_kernel<<<grid16, blk16, 0, stream>>>(fH, Xc, R, nullptr, 0);
            gemm_nn_kernel<<<grid16, blk16, 0, stream>>>(Xc, R, Xn, Xc, 1);
            float* tmp = Xc; Xc = Xn; Xn = tmp;
        }

        finalize_kernel<<<(F * F + F + 255) / 256, 256, 0, stream>>>(Xc, out);
    }
}

// Round 9
// 398.682 us; speedup vs baseline: 1.1993x; 1.1993x over previous
//
#include <hip/hip_runtime.h>
#include <math.h>

#define F 1024
#define NROWS 8192
#define NELEM (NROWS * F)

typedef unsigned short ushort_t;
typedef short bf16x8 __attribute__((ext_vector_type(8)));
typedef float f32x4 __attribute__((ext_vector_type(4)));
typedef unsigned short ushort8 __attribute__((ext_vector_type(8)));

__device__ __forceinline__ ushort_t f2bf(float f) {
  unsigned u = __float_as_uint(f);
  unsigned r = (u + 0x7fffu + ((u >> 16) & 1u)) >> 16;
  return (ushort_t)r;
}
__device__ __forceinline__ float bf2f(ushort_t b) {
  return __uint_as_float(((unsigned)b) << 16);
}

typedef const __attribute__((address_space(1))) unsigned int* gas_ptr;
typedef __attribute__((address_space(3))) unsigned int* las_ptr;
__device__ __forceinline__ void gload16(const void* g, const void* l) {
  __builtin_amdgcn_global_load_lds((gas_ptr)(unsigned long long)g,
                                   (las_ptr)(unsigned int)(unsigned long long)l,
                                   16, 0, 0);
}

// ---------------- tconv + fused sumsq ----------------
__global__ __launch_bounds__(256) void tconv_kernel(const float* __restrict__ x,
                                                    ushort_t* __restrict__ xthi,
                                                    ushort_t* __restrict__ xtlo,
                                                    float* __restrict__ partial) {
    __shared__ ushort_t th[64][68];
    __shared__ ushort_t tl[64][68];
    __shared__ float sdata[256];
    int c0 = blockIdx.x * 64;
    int r0 = blockIdx.y * 64;
    int tid = threadIdx.x;
    float ss = 0.f;
#pragma unroll
    for (int i = 0; i < 4; ++i) {
        int q = tid + 256 * i;
        int r = q >> 4;
        int cq = (q & 15) << 2;
        float4 vx = *(const float4*)&x[(size_t)(r0 + r) * 1024 + c0 + cq];
        float vv[4] = {vx.x, vx.y, vx.z, vx.w};
#pragma unroll
        for (int j = 0; j < 4; ++j) {
            ss = fmaf(vv[j], vv[j], ss);
            ushort_t h = f2bf(vv[j]);
            ushort_t l = f2bf(vv[j] - bf2f(h));
            th[r][cq + j] = h;
            tl[r][cq + j] = l;
        }
    }
    sdata[tid] = ss;
    __syncthreads();
    for (int off = 128; off > 0; off >>= 1) {
        if (tid < off) sdata[tid] += sdata[tid + off];
        __syncthreads();
    }
    if (tid == 0) partial[blockIdx.y * 16 + blockIdx.x] = sdata[0];
#pragma unroll
    for (int i = 0; i < 2; ++i) {
        int q = tid + 256 * i;
        int c = q >> 3;
        int rq = (q & 7) << 3;
        ushort8 oh, ol;
#pragma unroll
        for (int j = 0; j < 8; ++j) {
            oh[j] = th[rq + j][c];
            ol[j] = tl[rq + j][c];
        }
        *(ushort8*)&xthi[(size_t)(c0 + c) * 8192 + r0 + rq] = oh;
        *(ushort8*)&xtlo[(size_t)(c0 + c) * 8192 + r0 + rq] = ol;
    }
}

// ---------------- SYRK 256x256: 10 triangle tiles, full NZ=16 / diag NZ=8, 1024 thr ----------------
// Register-budget: 4 waves/SIMD -> 128 unified regs/thread. acc 64 + ah/al 32 + per-fn bh/bl 8 + addr ~15.
__device__ __forceinline__ void stage256(const ushort_t* __restrict__ gp, int row0, int kk,
                                         ushort_t* sbase, int tid) {
    int r = tid >> 2, pos = tid & 3;
    int kc = (pos ^ ((r >> 1) & 3)) << 3;
    gload16(gp + (size_t)(row0 + r) * 8192 + kk + kc, sbase + ((tid >> 6) << 9));
}

__global__ __launch_bounds__(1024, 4) void syrk256_kernel(
    const ushort_t* __restrict__ XThi, const ushort_t* __restrict__ XTlo,
    float* __restrict__ P)
{
    __shared__ ushort_t smem[65536];   // 128 KB
    int id = blockIdx.x;
    int tid = threadIdx.x, lane = tid & 63, w = tid >> 6;
    int wm = w >> 2, wn = w & 3;       // 4x4 wave grid, 64x64 per wave
    int lr = lane & 15, cg = lane >> 4;

    bool isfull = id < 96;
    int bi, bj, k0, sliceBase;
    if (isfull) {
        int f = id >> 4;
        int z = id & 15;
        bi = 1;
        while (bi * (bi + 1) / 2 <= f) ++bi;
        bj = f - bi * (bi - 1) / 2;
        k0 = z << 9;                   // K-chunk 512
        sliceBase = (f << 4) + z;
    } else {
        int d = (id - 96) >> 3;
        int z = (id - 96) & 7;
        bi = d; bj = d;
        k0 = z << 10;                  // K-chunk 1024
        sliceBase = 96 + (d << 3) + z;
    }
    int arow0 = bi << 8, brow0 = bj << 8;

    f32x4 zero4 = {0.f, 0.f, 0.f, 0.f};
    f32x4 acc[4][4];
#pragma unroll
    for (int a = 0; a < 4; ++a)
#pragma unroll
        for (int b = 0; b < 4; ++b) acc[a][b] = zero4;

#define S2_STAGE_F(BUF, KT)                                                        \
    {                                                                              \
        ushort_t* sb = smem + (BUF) * 32768;                                       \
        int kk = k0 + ((KT) << 5);                                                 \
        stage256(XThi, arow0, kk, sb + 0, tid);                                    \
        stage256(XTlo, arow0, kk, sb + 8192, tid);                                 \
        stage256(XThi, brow0, kk, sb + 16384, tid);                                \
        stage256(XTlo, brow0, kk, sb + 24576, tid);                                \
    }

#define S2_STAGE_D(BUF, KT)                                                        \
    {                                                                              \
        ushort_t* sb = smem + (BUF) * 16384;                                       \
        int kk = k0 + ((KT) << 5);                                                 \
        stage256(XThi, arow0, kk, sb + 0, tid);                                    \
        stage256(XTlo, arow0, kk, sb + 8192, tid);                                 \
    }

// low register-pressure compute: A fragments resident, B loaded per-fn
#define S2_COMP(SB, ALO, BH, BL)                                                   \
    {                                                                              \
        const ushort_t* sb = (SB);                                                 \
        int xo = (cg ^ ((lr >> 1) & 3)) << 3;                                      \
        bf16x8 ah[4], al[4];                                                       \
        _Pragma("unroll")                                                          \
        for (int fx = 0; fx < 4; ++fx) {                                           \
            int ao = ((wm << 6) + (fx << 4) + lr) * 32 + xo;                       \
            ah[fx] = *(const bf16x8*)&sb[0 + ao];                                  \
            al[fx] = *(const bf16x8*)&sb[(ALO) + ao];                              \
        }                                                                          \
        _Pragma("unroll")                                                          \
        for (int fn = 0; fn < 4; ++fn) {                                           \
            int bo = ((wn << 6) + (fn << 4) + lr) * 32 + xo;                       \
            bf16x8 bh = *(const bf16x8*)&sb[(BH) + bo];                            \
            bf16x8 bl = *(const bf16x8*)&sb[(BL) + bo];                            \
            _Pragma("unroll")                                                      \
            for (int fm = 0; fm < 4; ++fm) {                                       \
                acc[fm][fn] = __builtin_amdgcn_mfma_f32_16x16x32_bf16(             \
                    ah[fm], bh, acc[fm][fn], 0, 0, 0);                             \
                acc[fm][fn] = __builtin_amdgcn_mfma_f32_16x16x32_bf16(             \
                    ah[fm], bl, acc[fm][fn], 0, 0, 0);                             \
                acc[fm][fn] = __builtin_amdgcn_mfma_f32_16x16x32_bf16(             \
                    al[fm], bh, acc[fm][fn], 0, 0, 0);                             \
            }                                                                      \
        }                                                                          \
    }

    if (isfull) {
        S2_STAGE_F(0, 0)
        for (int kt = 0; kt < 15; ++kt) {
            if ((kt & 1) == 0) S2_STAGE_F(1, kt + 1) else S2_STAGE_F(0, kt + 1)
            asm volatile("s_waitcnt vmcnt(4)" ::: "memory");
            __builtin_amdgcn_s_barrier();
            __builtin_amdgcn_sched_barrier(0);
            if ((kt & 1) == 0) S2_COMP(smem + 0, 8192, 16384, 24576)
            else               S2_COMP(smem + 32768, 8192, 16384, 24576)
            __builtin_amdgcn_sched_barrier(0);
            __builtin_amdgcn_s_barrier();
        }
        asm volatile("s_waitcnt vmcnt(0)" ::: "memory");
        __builtin_amdgcn_s_barrier();
        __builtin_amdgcn_sched_barrier(0);
        S2_COMP(smem + 32768, 8192, 16384, 24576)   // kt=15 -> slot 1
    } else {
        S2_STAGE_D(0, 0)
        for (int kt = 0; kt < 31; ++kt) {
            if ((kt & 1) == 0) S2_STAGE_D(1, kt + 1) else S2_STAGE_D(0, kt + 1)
            asm volatile("s_waitcnt vmcnt(2)" ::: "memory");
            __builtin_amdgcn_s_barrier();
            __builtin_amdgcn_sched_barrier(0);
            if ((kt & 1) == 0) S2_COMP(smem + 0, 8192, 0, 8192)
            else               S2_COMP(smem + 16384, 8192, 0, 8192)
            __builtin_amdgcn_sched_barrier(0);
            __builtin_amdgcn_s_barrier();
        }
        asm volatile("s_waitcnt vmcnt(0)" ::: "memory");
        __builtin_amdgcn_s_barrier();
        __builtin_amdgcn_sched_barrier(0);
        S2_COMP(smem + 16384, 8192, 0, 8192)        // kt=31 -> slot 1
    }

    float* Pt = P + ((size_t)sliceBase << 16);
#pragma unroll
    for (int fm = 0; fm < 4; ++fm)
#pragma unroll
        for (int fn = 0; fn < 4; ++fn)
#pragma unroll
            for (int rr = 0; rr < 4; ++rr) {
                int row = (wm << 6) + (fm << 4) + (cg << 2) + rr;
                int col = (wn << 6) + (fn << 4) + lr;
                Pt[row * 256 + col] = acc[fm][fn][rr];
            }
}

// ---------------- reduceH: fused damp + z-sum (16 full / 8 diag) + split + mirror ----------------
__global__ void reduceH_kernel(const float* __restrict__ P, const float* __restrict__ part,
                               ushort_t* __restrict__ Hhi, ushort_t* __restrict__ Hlo) {
    __shared__ float red[256];
    int tid = threadIdx.x;
    float s0 = 0.f;
    for (int i = tid; i < 2048; i += 256) s0 += part[i];
    red[tid] = s0;
    __syncthreads();
    for (int off = 128; off > 0; off >>= 1) {
        if (tid < off) red[tid] += red[tid + off];
        __syncthreads();
    }
    float damp = 0.01f * (red[0] / (float)NELEM);

    int b = blockIdx.x;                 // 640 blocks
    int tile = b >> 6;                  // 0..9
    int li = ((b & 63) << 10) + (tid << 2);
    int bi, bj, base, nz;
    if (tile < 6) {
        int f = tile;
        bi = 1;
        while (bi * (bi + 1) / 2 <= f) ++bi;
        bj = f - bi * (bi - 1) / 2;
        base = f << 4;  nz = 16;
    } else {
        int d = tile - 6;
        bi = d; bj = d;
        base = 96 + (d << 3);  nz = 8;
    }
    const float* Pt = P + ((size_t)base << 16);
    float sx = 0.f, sy = 0.f, sz = 0.f, sw = 0.f;
    for (int zz = 0; zz < nz; ++zz) {
        float4 p4 = *(const float4*)&Pt[((size_t)zz << 16) + li];
        sx += p4.x; sy += p4.y; sz += p4.z; sw += p4.w;
    }
    int r = li >> 8, c = li & 255;
    int gi = (bi << 8) + r;
    float v4[4] = {sx, sy, sz, sw};
#pragma unroll
    for (int k = 0; k < 4; ++k) {
        int gj = (bj << 8) + c + k;
        float val = v4[k];
        if (gi == gj) val += damp;
        ushort_t h = f2bf(val), l = f2bf(val - bf2f(h));
        Hhi[gi * F + gj] = h;
        Hlo[gi * F + gj] = l;
        if (bi != bj) {
            Hhi[gj * F + gi] = h;
            Hlo[gj * F + gi] = l;
        }
    }
}

// ---------------- single matvec: y = H * ones (bf16 H) ----------------
__global__ void matvec_bf16_kernel(const ushort_t* __restrict__ Hhi, const float* __restrict__ v,
                                   float* __restrict__ y, int first) {
    __shared__ float sdata[256];
    int row = blockIdx.x, tid = threadIdx.x;
    float s = 0.f;
    if (first) {
        for (int j = tid; j < F; j += 256) s += bf2f(Hhi[row * F + j]);
    } else {
        for (int j = tid; j < F; j += 256) s = fmaf(bf2f(Hhi[row * F + j]), v[j], s);
    }
    sdata[tid] = s;
    __syncthreads();
    for (int off = 128; off > 0; off >>= 1) {
        if (tid < off) sdata[tid] += sdata[tid + off];
        __syncthreads();
    }
    if (tid == 0) y[row] = sdata[0];
}

// ---------------- initX1: lam = ||y||/32, c = 1/(1.15 lam), X1 = 2cI - c^2 H ----------------
__global__ void initX1_kernel(const ushort_t* __restrict__ Hhi, const ushort_t* __restrict__ Hlo,
                              ushort_t* __restrict__ Xhi, ushort_t* __restrict__ Xlo,
                              const float* __restrict__ y, float* __restrict__ scal) {
    __shared__ float red[256];
    int tid = threadIdx.x;
    float4 a = ((const float4*)y)[tid];
    float s = a.x * a.x + a.y * a.y + a.z * a.z + a.w * a.w;
    red[tid] = s;
    __syncthreads();
    for (int off = 128; off > 0; off >>= 1) {
        if (tid < off) red[tid] += red[tid + off];
        __syncthreads();
    }
    float lam = sqrtf(red[0]) * (1.0f / 32.0f);
    float c = 1.0f / (1.15f * lam);
    if (blockIdx.x == 0 && tid == 0) { scal[2] = lam; scal[3] = c; }
    float c2 = c * c;
    int idx0 = (blockIdx.x * 256 + tid) * 4;
#pragma unroll
    for (int k = 0; k < 4; ++k) {
        int idx = idx0 + k;
        float hv = bf2f(Hhi[idx]) + bf2f(Hlo[idx]);
        float val = -c2 * hv + (((idx >> 10) == (idx & 1023)) ? 2.f * c : 0.f);
        ushort_t h = f2bf(val);
        Xhi[idx] = h;
        Xlo[idx] = f2bf(val - bf2f(h));
    }
}

// ---------------- NS GEMM: 64x64 tile, K=1024, ring-4 prefetch-2 (measured body) ----------------
__device__ __forceinline__ void stage64(const ushort_t* __restrict__ gp, int row0, int kk,
                                        ushort_t* sbase, int tid) {
    int r = tid >> 2, pos = tid & 3;
    int kc = (pos ^ ((r >> 1) & 3)) << 3;
    gload16(gp + (size_t)(row0 + r) * 1024 + kk + kc, sbase + (size_t)(tid >> 6 << 9));
}

template <int TERMS, int MODE>
__global__ __launch_bounds__(256) void ns_gemm_kernel(
    const ushort_t* __restrict__ Ahi, const ushort_t* __restrict__ Alo,
    const ushort_t* __restrict__ Bhi, const ushort_t* __restrict__ Blo,
    const ushort_t* __restrict__ Xchi, const ushort_t* __restrict__ Xclo,
    ushort_t* __restrict__ Ohi, ushort_t* __restrict__ Olo,
    float* __restrict__ Of)
{
    constexpr int SLOT = (TERMS == 3) ? 8192 : 4096;
    __shared__ ushort_t smem[4 * SLOT];
    int tid = threadIdx.x, lane = tid & 63, w = tid >> 6;
    int wm = w >> 1, wn = w & 1;
    int row0 = blockIdx.y * 64, col0 = blockIdx.x * 64;
    int lr = lane & 15, cg = lane >> 4;

    f32x4 zero4 = {0.f, 0.f, 0.f, 0.f};
    f32x4 acc[2][2];
#pragma unroll
    for (int a = 0; a < 2; ++a)
#pragma unroll
        for (int b = 0; b < 2; ++b) acc[a][b] = zero4;

#define NS_STAGE(KT)                                                               \
    {                                                                              \
        ushort_t* sb = smem + (size_t)((KT) & 3) * SLOT;                           \
        int kk = (KT) << 5;                                                        \
        stage64(Ahi, row0, kk, sb + 0, tid);                                       \
        stage64(Bhi, col0, kk, sb + 2048, tid);                                    \
        if constexpr (TERMS == 3) {                                                \
            stage64(Alo, row0, kk, sb + 4096, tid);                                \
            stage64(Blo, col0, kk, sb + 6144, tid);                                \
        }                                                                          \
    }

#define NS_COMPUTE(KT)                                                             \
    {                                                                              \
        const ushort_t* sb = smem + (size_t)((KT) & 3) * SLOT;                     \
        bf16x8 ah[2], bh[2], al[2], bl[2];                                         \
        _Pragma("unroll")                                                          \
        for (int fx = 0; fx < 2; ++fx) {                                           \
            int xo = (cg ^ ((lr >> 1) & 3)) << 3;                                  \
            int ao = ((wm << 5) + (fx << 4) + lr) * 32 + xo;                       \
            int bo = ((wn << 5) + (fx << 4) + lr) * 32 + xo;                       \
            ah[fx] = *(const bf16x8*)&sb[0 + ao];                                  \
            bh[fx] = *(const bf16x8*)&sb[2048 + bo];                               \
            if constexpr (TERMS == 3) {                                            \
                al[fx] = *(const bf16x8*)&sb[4096 + ao];                           \
                bl[fx] = *(const bf16x8*)&sb[6144 + bo];                           \
            }                                                                      \
        }                                                                          \
        _Pragma("unroll")                                                          \
        for (int fm = 0; fm < 2; ++fm)                                             \
            _Pragma("unroll")                                                      \
            for (int fn = 0; fn < 2; ++fn) {                                       \
                acc[fm][fn] = __builtin_amdgcn_mfma_f32_16x16x32_bf16(             \
                    ah[fm], bh[fn], acc[fm][fn], 0, 0, 0);                         \
                if constexpr (TERMS == 3) {                                        \
                    acc[fm][fn] = __builtin_amdgcn_mfma_f32_16x16x32_bf16(         \
                        ah[fm], bl[fn], acc[fm][fn], 0, 0, 0);                     \
                    acc[fm][fn] = __builtin_amdgcn_mfma_f32_16x16x32_bf16(         \
                        al[fm], bh[fn], acc[fm][fn], 0, 0, 0);                     \
                }                                                                  \
            }                                                                      \
    }

    NS_STAGE(0)
    NS_STAGE(1)
    for (int kt = 0; kt < 30; ++kt) {
        NS_STAGE(kt + 2)
        if constexpr (TERMS == 3) { asm volatile("s_waitcnt vmcnt(8)" ::: "memory"); }
        else                      { asm volatile("s_waitcnt vmcnt(4)" ::: "memory"); }
        __builtin_amdgcn_s_barrier();
        __builtin_amdgcn_sched_barrier(0);
        NS_COMPUTE(kt)
        __builtin_amdgcn_sched_barrier(0);
    }
    if constexpr (TERMS == 3) { asm volatile("s_waitcnt vmcnt(4)" ::: "memory"); }
    else                      { asm volatile("s_waitcnt vmcnt(2)" ::: "memory"); }
    __builtin_amdgcn_s_barrier();
    __builtin_amdgcn_sched_barrier(0);
    NS_COMPUTE(30)
    asm volatile("s_waitcnt vmcnt(0)" ::: "memory");
    __builtin_amdgcn_s_barrier();
    __builtin_amdgcn_sched_barrier(0);
    NS_COMPUTE(31)

#pragma unroll
    for (int fm = 0; fm < 2; ++fm)
#pragma unroll
        for (int fn = 0; fn < 2; ++fn)
#pragma unroll
            for (int rr = 0; rr < 4; ++rr) {
                int r = row0 + (wm << 5) + fm * 16 + cg * 4 + rr;
                int c = col0 + (wn << 5) + fn * 16 + lr;
                size_t idx = (size_t)r * F + c;
                float val = acc[fm][fn][rr];
                if constexpr (MODE == 0) {
                    ushort_t h = f2bf(val);
                    Ohi[idx] = h;
                    Olo[idx] = f2bf(val - bf2f(h));
                } else {
                    float xc = bf2f(Xchi[idx]) + bf2f(Xclo[idx]);
                    val = 2.0f * xc - val;
                    if constexpr (MODE == 1) {
                        ushort_t h = f2bf(val);
                        Ohi[idx] = h;
                        Olo[idx] = f2bf(val - bf2f(h));
                    } else {
                        Of[idx] = val;
                    }
                }
            }
    if constexpr (MODE == 2) {
        if (blockIdx.x == 0 && blockIdx.y == 0) {
            int i0 = tid * 4;
#pragma unroll
            for (int k = 0; k < 4; ++k)
                Of[(size_t)F * F + i0 + k] = (float)(i0 + k);
        }
    }
}

// ======================= fp32 ultra-fallback =======================
__global__ void sumsq_partial_kernel(const float* __restrict__ x, float* __restrict__ partial) {
    __shared__ float sdata[256];
    int tid = threadIdx.x;
    int base = blockIdx.x * 4096;
    float s = 0.f;
    for (int i = tid; i < 4096; i += 256) {
        float v = x[base + i];
        s = fmaf(v, v, s);
    }
    sdata[tid] = s;
    __syncthreads();
    for (int off = 128; off > 0; off >>= 1) {
        if (tid < off) sdata[tid] += sdata[tid + off];
        __syncthreads();
    }
    if (tid == 0) partial[blockIdx.x] = sdata[0];
}

__global__ void finish_damp_kernel(const float* __restrict__ partial, float* __restrict__ scal) {
    __shared__ float sdata[256];
    int tid = threadIdx.x;
    float s = 0.f;
    for (int i = tid; i < 2048; i += 256) s += partial[i];
    sdata[tid] = s;
    __syncthreads();
    for (int off = 128; off > 0; off >>= 1) {
        if (tid < off) sdata[tid] += sdata[tid + off];
        __syncthreads();
    }
    if (tid == 0) {
        float mean = sdata[0] / (float)NELEM;
        scal[1] = 0.01f * mean;
    }
}

__global__ void init_v_kernel(float* __restrict__ v) {
    int i = blockIdx.x * 256 + threadIdx.x;
    if (i < F) v[i] = 1.0f;
}

__global__ void matvec_kernel(const float* __restrict__ H, const float* __restrict__ v,
                              float* __restrict__ y) {
    __shared__ float sdata[256];
    int row = blockIdx.x, tid = threadIdx.x;
    float s = 0.f;
    for (int j = tid; j < F; j += 256) s = fmaf(H[row * F + j], v[j], s);
    sdata[tid] = s;
    __syncthreads();
    for (int off = 128; off > 0; off >>= 1) {
        if (tid < off) sdata[tid] += sdata[tid + off];
        __syncthreads();
    }
    if (tid == 0) y[row] = sdata[0];
}

__global__ void normalize_kernel(const float* __restrict__ y, float* __restrict__ v,
                                 float* __restrict__ scal) {
    __shared__ float sdata[256];
    __shared__ float lam;
    int tid = threadIdx.x;
    float s = 0.f;
    for (int i = tid; i < F; i += 256) {
        float t = y[i];
        s = fmaf(t, t, s);
    }
    sdata[tid] = s;
    __syncthreads();
    for (int off = 128; off > 0; off >>= 1) {
        if (tid < off) sdata[tid] += sdata[tid + off];
        __syncthreads();
    }
    if (tid == 0) {
        lam = sqrtf(sdata[0]);
        scal[2] = lam;
        scal[3] = 1.0f / (1.05f * lam);
    }
    __syncthreads();
    float il = 1.0f / lam;
    for (int i = tid; i < F; i += 256) v[i] = y[i] * il;
}

__global__ __launch_bounds__(256) void syrk_kernel(const float* __restrict__ X,
                                                   float* __restrict__ H,
                                                   const float* __restrict__ scal) {
    __shared__ float LA[16][64];
    __shared__ float LB[16][64];
    int tx = threadIdx.x, ty = threadIdx.y;
    int t = ty * 16 + tx;
    int i0 = blockIdx.y * 64, j0 = blockIdx.x * 64;
    int lk = t >> 4;
    int lc = (t & 15) << 2;
    float acc[4][4] = {};
    for (int k0 = 0; k0 < NROWS; k0 += 16) {
        int r = (k0 + lk) * F;
        float4 a4 = *(const float4*)&X[r + i0 + lc];
        float4 b4 = *(const float4*)&X[r + j0 + lc];
        __syncthreads();
        *(float4*)&LA[lk][lc] = a4;
        *(float4*)&LB[lk][lc] = b4;
        __syncthreads();
#pragma unroll
        for (int kk = 0; kk < 16; ++kk) {
            float4 a = *(const float4*)&LA[kk][ty << 2];
            float4 b = *(const float4*)&LB[kk][tx << 2];
            float av[4] = {a.x, a.y, a.z, a.w};
            float bv[4] = {b.x, b.y, b.z, b.w};
#pragma unroll
            for (int rr = 0; rr < 4; ++rr)
#pragma unroll
                for (int cc = 0; cc < 4; ++cc)
                    acc[rr][cc] = fmaf(av[rr], bv[cc], acc[rr][cc]);
        }
    }
    float damp = scal[1];
#pragma unroll
    for (int rr = 0; rr < 4; ++rr) {
        int i = i0 + (ty << 2) + rr;
#pragma unroll
        for (int cc = 0; cc < 4; ++cc) {
            int j = j0 + (tx << 2) + cc;
            float v = acc[rr][cc];
            if (i == j) v += damp;
            H[i * F + j] = v;
        }
    }
}

__global__ void init_X_kernel(float* __restrict__ A, const float* __restrict__ scal) {
    int idx = blockIdx.x * 256 + threadIdx.x;
    int i = idx >> 10, j = idx & (F - 1);
    A[idx] = (i == j) ? scal[3] : 0.0f;
}

__global__ __launch_bounds__(256) void gemm_nn_kernel(const float* __restrict__ A,
                                                      const float* __restrict__ Bm,
                                                      float* __restrict__ C,
                                                      const float* __restrict__ D,
                                                      int mode) {
    __shared__ float LA[16][64];
    __shared__ float LB[16][64];
    int tx = threadIdx.x, ty = threadIdx.y;
    int t = ty * 16 + tx;
    int i0 = blockIdx.y * 64, j0 = blockIdx.x * 64;
    int aii = t >> 2;
    int akq = (t & 3) << 2;
    int bkk = t >> 4;
    int bjq = (t & 15) << 2;
    float acc[4][4] = {};
    for (int k0 = 0; k0 < F; k0 += 16) {
        float4 a4 = *(const float4*)&A[(i0 + aii) * F + k0 + akq];
        float4 b4 = *(const float4*)&Bm[(k0 + bkk) * F + j0 + bjq];
        __syncthreads();
        LA[akq + 0][aii] = a4.x;
        LA[akq + 1][aii] = a4.y;
        LA[akq + 2][aii] = a4.z;
        LA[akq + 3][aii] = a4.w;
        *(float4*)&LB[bkk][bjq] = b4;
        __syncthreads();
#pragma unroll
        for (int kk = 0; kk < 16; ++kk) {
            float4 a = *(const float4*)&LA[kk][ty << 2];
            float4 b = *(const float4*)&LB[kk][tx << 2];
            float av[4] = {a.x, a.y, a.z, a.w};
            float bv[4] = {b.x, b.y, b.z, b.w};
#pragma unroll
            for (int rr = 0; rr < 4; ++rr)
#pragma unroll
                for (int cc = 0; cc < 4; ++cc)
                    acc[rr][cc] = fmaf(av[rr], bv[cc], acc[rr][cc]);
        }
    }
#pragma unroll
    for (int rr = 0; rr < 4; ++rr) {
        int i = i0 + (ty << 2) + rr;
#pragma unroll
        for (int cc = 0; cc < 4; ++cc) {
            int j = j0 + (tx << 2) + cc;
            float v = acc[rr][cc];
            if (mode == 1) v = 2.0f * D[i * F + j] - v;
            C[i * F + j] = v;
        }
    }
}

__global__ void finalize_kernel(const float* __restrict__ A, float* __restrict__ out) {
    int idx = blockIdx.x * 256 + threadIdx.x;
    if (idx < F * F) out[idx] = A[idx];
    else if (idx < F * F + F) out[idx] = (float)(idx - F * F);
}

// ======================= launch =======================
extern "C" void kernel_launch(void* const* d_in, const int* in_sizes, int n_in,
                              void* d_out, int out_size, void* d_ws, size_t ws_size,
                              hipStream_t stream) {
    const float* x = (const float*)d_in[0];
    float* out = (float*)d_out;

    char* base = (char*)d_ws;
    size_t off = 0;
    auto alloc = [&](size_t bytes) -> char* {
        char* p = base + off;
        off += bytes;
        off = (off + 255) & ~(size_t)255;
        return p;
    };
    float*    scal = (float*)alloc(64 * 4);
    float*    part = (float*)alloc(2048 * 4);
    ushort_t* XThi = (ushort_t*)alloc((size_t)NELEM * 2);
    ushort_t* XTlo = (ushort_t*)alloc((size_t)NELEM * 2);
    ushort_t* Hhi  = (ushort_t*)alloc((size_t)F * F * 2);
    ushort_t* Hlo  = (ushort_t*)alloc((size_t)F * F * 2);
    ushort_t* X0hi = (ushort_t*)alloc((size_t)F * F * 2);
    ushort_t* X0lo = (ushort_t*)alloc((size_t)F * F * 2);
    ushort_t* X1hi = (ushort_t*)alloc((size_t)F * F * 2);
    ushort_t* X1lo = (ushort_t*)alloc((size_t)F * F * 2);
    ushort_t* Shi  = (ushort_t*)alloc((size_t)F * F * 2);
    ushort_t* Slo  = (ushort_t*)alloc((size_t)F * F * 2);
    float*    v    = (float*)alloc(F * 4);
    float*    y    = (float*)alloc(F * 4);
    float*    P    = (float*)alloc((size_t)128 * 65536 * 4);   // 32 MB
    size_t need = off;

    if (ws_size >= need) {
        // ======== MFMA path ========
        tconv_kernel<<<dim3(16, 128), 256, 0, stream>>>(x, XThi, XTlo, part);

        syrk256_kernel<<<128, 1024, 0, stream>>>(XThi, XTlo, P);
        reduceH_kernel<<<640, 256, 0, stream>>>(P, part, Hhi, Hlo);

        matvec_bf16_kernel<<<F, 256, 0, stream>>>(Hhi, v, y, 1);
        initX1_kernel<<<1024, 256, 0, stream>>>(Hhi, Hlo, X0hi, X0lo, y, scal);

        ushort_t* xch = X0hi; ushort_t* xcl = X0lo;
        ushort_t* xnh = X1hi; ushort_t* xnl = X1lo;
        dim3 g(16, 16);
        for (int it = 0; it < 4; ++it) {
            bool last = (it == 3);
            if (it < 1) {
                ns_gemm_kernel<1, 0><<<g, 256, 0, stream>>>(xch, xcl, Hhi, Hlo,
                                                            nullptr, nullptr, Shi, Slo, nullptr);
                ns_gemm_kernel<1, 1><<<g, 256, 0, stream>>>(Shi, Slo, xch, xcl,
                                                            xch, xcl, xnh, xnl, nullptr);
            } else {
                ns_gemm_kernel<3, 0><<<g, 256, 0, stream>>>(xch, xcl, Hhi, Hlo,
                                                            nullptr, nullptr, Shi, Slo, nullptr);
                if (last)
                    ns_gemm_kernel<3, 2><<<g, 256, 0, stream>>>(Shi, Slo, xch, xcl,
                                                                xch, xcl, nullptr, nullptr, out);
                else
                    ns_gemm_kernel<3, 1><<<g, 256, 0, stream>>>(Shi, Slo, xch, xcl,
                                                                xch, xcl, xnh, xnl, nullptr);
            }
            ushort_t* th = xch; xch = xnh; xnh = th;
            ushort_t* tl = xcl; xcl = xnl; xnl = tl;
        }
    } else {
        // -------- fp32 ultra-fallback --------
        float* ws = (float*)d_ws;
        float* fscal    = ws;
        float* fpartial = ws + 64;
        float* fH  = ws + 4096;
        float* fA  = fH + F * F;
        float* fB  = fA + F * F;
        float* fv  = fB + F * F;
        float* fy  = fv + F;
        float* R = out;

        sumsq_partial_kernel<<<2048, 256, 0, stream>>>(x, fpartial);
        finish_damp_kernel<<<1, 256, 0, stream>>>(fpartial, fscal);

        dim3 grid16(16, 16), blk16(16, 16);
        syrk_kernel<<<grid16, blk16, 0, stream>>>(x, fH, fscal);

        init_v_kernel<<<4, 256, 0, stream>>>(fv);
        for (int it = 0; it < 12; ++it) {
            matvec_kernel<<<F, 256, 0, stream>>>(fH, fv, fy);
            normalize_kernel<<<1, 256, 0, stream>>>(fy, fv, fscal);
        }

        init_X_kernel<<<(F * F) / 256, 256, 0, stream>>>(fA, fscal);
        float* Xc = fA;
        float* Xn = fB;
        for (int it = 0; it < 8; ++it) {
            gemm_nn_kernel<<<grid16, blk16, 0, stream>>>(fH, Xc, R, nullptr, 0);
            gemm_nn_kernel<<<grid16, blk16, 0, stream>>>(Xc, R, Xn, Xc, 1);
            float* tmp = Xc; Xc = Xn; Xn = tmp;
        }

        finalize_kernel<<<(F * F + F + 255) / 256, 256, 0, stream>>>(Xc, out);
    }
}

// Round 10
// 354.771 us; speedup vs baseline: 1.3477x; 1.1238x over previous
//
#include <hip/hip_runtime.h>
#include <math.h>

#define F 1024
#define NROWS 8192
#define NELEM (NROWS * F)

typedef unsigned short ushort_t;
typedef short bf16x8 __attribute__((ext_vector_type(8)));
typedef float f32x4 __attribute__((ext_vector_type(4)));
typedef unsigned short ushort8 __attribute__((ext_vector_type(8)));

__device__ __forceinline__ ushort_t f2bf(float f) {
  unsigned u = __float_as_uint(f);
  unsigned r = (u + 0x7fffu + ((u >> 16) & 1u)) >> 16;
  return (ushort_t)r;
}
__device__ __forceinline__ float bf2f(ushort_t b) {
  return __uint_as_float(((unsigned)b) << 16);
}

typedef const __attribute__((address_space(1))) unsigned int* gas_ptr;
typedef __attribute__((address_space(3))) unsigned int* las_ptr;
__device__ __forceinline__ void gload16(const void* g, const void* l) {
  __builtin_amdgcn_global_load_lds((gas_ptr)(unsigned long long)g,
                                   (las_ptr)(unsigned int)(unsigned long long)l,
                                   16, 0, 0);
}

// ---------------- tconv + fused sumsq ----------------
__global__ __launch_bounds__(256) void tconv_kernel(const float* __restrict__ x,
                                                    ushort_t* __restrict__ xthi,
                                                    ushort_t* __restrict__ xtlo,
                                                    float* __restrict__ partial) {
    __shared__ ushort_t th[64][68];
    __shared__ ushort_t tl[64][68];
    __shared__ float sdata[256];
    int c0 = blockIdx.x * 64;
    int r0 = blockIdx.y * 64;
    int tid = threadIdx.x;
    float ss = 0.f;
#pragma unroll
    for (int i = 0; i < 4; ++i) {
        int q = tid + 256 * i;
        int r = q >> 4;
        int cq = (q & 15) << 2;
        float4 vx = *(const float4*)&x[(size_t)(r0 + r) * 1024 + c0 + cq];
        float vv[4] = {vx.x, vx.y, vx.z, vx.w};
#pragma unroll
        for (int j = 0; j < 4; ++j) {
            ss = fmaf(vv[j], vv[j], ss);
            ushort_t h = f2bf(vv[j]);
            ushort_t l = f2bf(vv[j] - bf2f(h));
            th[r][cq + j] = h;
            tl[r][cq + j] = l;
        }
    }
    sdata[tid] = ss;
    __syncthreads();
    for (int off = 128; off > 0; off >>= 1) {
        if (tid < off) sdata[tid] += sdata[tid + off];
        __syncthreads();
    }
    if (tid == 0) partial[blockIdx.y * 16 + blockIdx.x] = sdata[0];
#pragma unroll
    for (int i = 0; i < 2; ++i) {
        int q = tid + 256 * i;
        int c = q >> 3;
        int rq = (q & 7) << 3;
        ushort8 oh, ol;
#pragma unroll
        for (int j = 0; j < 8; ++j) {
            oh[j] = th[rq + j][c];
            ol[j] = tl[rq + j][c];
        }
        *(ushort8*)&xthi[(size_t)(c0 + c) * 8192 + r0 + rq] = oh;
        *(ushort8*)&xtlo[(size_t)(c0 + c) * 8192 + r0 + rq] = ol;
    }
}

// ---------------- SYRK 256x256: 512 threads, wave tile 128x64, full NZ=16 / diag NZ=8 ----------------
// 8 waves/CU = 2 waves/SIMD -> 256 unified regs/thread. acc 128 + Bfrag 32 + Atmp 8 + addr ~25.
__device__ __forceinline__ void stageS(const ushort_t* __restrict__ gp, int row0, int kk,
                                       ushort_t* sbase, int tid) {
#pragma unroll
    for (int q = 0; q < 2; ++q) {
        int c = ((tid >> 6) << 7) + (q << 6) + (tid & 63);  // chunk 0..1023
        int r = c >> 2, pos = c & 3;
        int kc = (pos ^ ((r >> 1) & 3)) << 3;
        gload16(gp + (size_t)(row0 + r) * 8192 + kk + kc,
                sbase + (size_t)((((tid >> 6) << 7) + (q << 6)) << 3));
    }
}

__global__ __launch_bounds__(512, 2) void syrk256_kernel(
    const ushort_t* __restrict__ XThi, const ushort_t* __restrict__ XTlo,
    float* __restrict__ P)
{
    __shared__ ushort_t smem[65536];   // 128 KB; full: 2 slots x (Ahi,Alo,Bhi,Blo x 8192)
    int id = blockIdx.x;
    int tid = threadIdx.x, lane = tid & 63, w = tid >> 6;
    int wm = w >> 2, wn = w & 3;       // 2x4 wave grid: wave tile 128x64
    int lr = lane & 15, cg = lane >> 4;

    bool isfull = id < 96;             // 6 full tiles x 16 slices
    int bi, bj, k0, sliceBase;
    if (isfull) {
        int f = id >> 4;
        int z = id & 15;
        bi = 1;
        while (bi * (bi + 1) / 2 <= f) ++bi;
        bj = f - bi * (bi - 1) / 2;
        k0 = z << 9;                   // K-chunk 512, 16 K-steps
        sliceBase = (f << 4) + z;
    } else {
        int d = (id - 96) >> 3;        // 4 diag tiles x 8 slices
        int z = (id - 96) & 7;
        bi = d; bj = d;
        k0 = z << 10;                  // K-chunk 1024, 32 K-steps
        sliceBase = 96 + (d << 3) + z;
    }
    int arow0 = bi << 8, brow0 = bj << 8;

    f32x4 zero4 = {0.f, 0.f, 0.f, 0.f};
    f32x4 acc[8][4];
#pragma unroll
    for (int a = 0; a < 8; ++a)
#pragma unroll
        for (int b = 0; b < 4; ++b) acc[a][b] = zero4;

#define S2_STAGE_F(BUF, KT)                                                        \
    {                                                                              \
        ushort_t* sb = smem + (BUF) * 32768;                                       \
        int kk = k0 + ((KT) << 5);                                                 \
        stageS(XThi, arow0, kk, sb + 0, tid);                                      \
        stageS(XTlo, arow0, kk, sb + 8192, tid);                                   \
        stageS(XThi, brow0, kk, sb + 16384, tid);                                  \
        stageS(XTlo, brow0, kk, sb + 24576, tid);                                  \
    }

#define S2_STAGE_D(BUF, KT)                                                        \
    {                                                                              \
        ushort_t* sb = smem + (BUF) * 16384;                                       \
        int kk = k0 + ((KT) << 5);                                                 \
        stageS(XThi, arow0, kk, sb + 0, tid);                                      \
        stageS(XTlo, arow0, kk, sb + 8192, tid);                                   \
    }

// B fragments resident (32 regs), A loaded per-fm (8 regs transient)
#define S2_COMP(SB, ALO, BH, BL)                                                   \
    {                                                                              \
        const ushort_t* sb = (SB);                                                 \
        int xo = (cg ^ ((lr >> 1) & 3)) << 3;                                      \
        bf16x8 bh[4], bl[4];                                                       \
        _Pragma("unroll")                                                          \
        for (int fn = 0; fn < 4; ++fn) {                                           \
            int bo = ((wn << 6) + (fn << 4) + lr) * 32 + xo;                       \
            bh[fn] = *(const bf16x8*)&sb[(BH) + bo];                               \
            bl[fn] = *(const bf16x8*)&sb[(BL) + bo];                               \
        }                                                                          \
        _Pragma("unroll")                                                          \
        for (int fm = 0; fm < 8; ++fm) {                                           \
            int ao = ((wm << 7) + (fm << 4) + lr) * 32 + xo;                       \
            bf16x8 ah = *(const bf16x8*)&sb[0 + ao];                               \
            bf16x8 al = *(const bf16x8*)&sb[(ALO) + ao];                           \
            _Pragma("unroll")                                                      \
            for (int fn = 0; fn < 4; ++fn) {                                       \
                acc[fm][fn] = __builtin_amdgcn_mfma_f32_16x16x32_bf16(             \
                    ah, bh[fn], acc[fm][fn], 0, 0, 0);                             \
                acc[fm][fn] = __builtin_amdgcn_mfma_f32_16x16x32_bf16(             \
                    ah, bl[fn], acc[fm][fn], 0, 0, 0);                             \
                acc[fm][fn] = __builtin_amdgcn_mfma_f32_16x16x32_bf16(             \
                    al, bh[fn], acc[fm][fn], 0, 0, 0);                             \
            }                                                                      \
        }                                                                          \
    }

    if (isfull) {
        S2_STAGE_F(0, 0)
        for (int kt = 0; kt < 15; ++kt) {
            if ((kt & 1) == 0) S2_STAGE_F(1, kt + 1) else S2_STAGE_F(0, kt + 1)
            asm volatile("s_waitcnt vmcnt(8)" ::: "memory");
            __builtin_amdgcn_s_barrier();
            __builtin_amdgcn_sched_barrier(0);
            if ((kt & 1) == 0) S2_COMP(smem + 0, 8192, 16384, 24576)
            else               S2_COMP(smem + 32768, 8192, 16384, 24576)
            __builtin_amdgcn_sched_barrier(0);
            __builtin_amdgcn_s_barrier();
        }
        asm volatile("s_waitcnt vmcnt(0)" ::: "memory");
        __builtin_amdgcn_s_barrier();
        __builtin_amdgcn_sched_barrier(0);
        S2_COMP(smem + 32768, 8192, 16384, 24576)   // kt=15 -> slot 1
    } else {
        S2_STAGE_D(0, 0)
        for (int kt = 0; kt < 31; ++kt) {
            if ((kt & 1) == 0) S2_STAGE_D(1, kt + 1) else S2_STAGE_D(0, kt + 1)
            asm volatile("s_waitcnt vmcnt(4)" ::: "memory");
            __builtin_amdgcn_s_barrier();
            __builtin_amdgcn_sched_barrier(0);
            if ((kt & 1) == 0) S2_COMP(smem + 0, 8192, 0, 8192)
            else               S2_COMP(smem + 16384, 8192, 0, 8192)
            __builtin_amdgcn_sched_barrier(0);
            __builtin_amdgcn_s_barrier();
        }
        asm volatile("s_waitcnt vmcnt(0)" ::: "memory");
        __builtin_amdgcn_s_barrier();
        __builtin_amdgcn_sched_barrier(0);
        S2_COMP(smem + 16384, 8192, 0, 8192)        // kt=31 -> slot 1
    }

    float* Pt = P + ((size_t)sliceBase << 16);
#pragma unroll
    for (int fm = 0; fm < 8; ++fm)
#pragma unroll
        for (int fn = 0; fn < 4; ++fn)
#pragma unroll
            for (int rr = 0; rr < 4; ++rr) {
                int row = (wm << 7) + (fm << 4) + (cg << 2) + rr;
                int col = (wn << 6) + (fn << 4) + lr;
                Pt[row * 256 + col] = acc[fm][fn][rr];
            }
}

// ---------------- reduceH: fused damp + z-sum (16 full / 8 diag) + split + mirror ----------------
__global__ void reduceH_kernel(const float* __restrict__ P, const float* __restrict__ part,
                               ushort_t* __restrict__ Hhi, ushort_t* __restrict__ Hlo) {
    __shared__ float red[256];
    int tid = threadIdx.x;
    float s0 = 0.f;
    for (int i = tid; i < 2048; i += 256) s0 += part[i];
    red[tid] = s0;
    __syncthreads();
    for (int off = 128; off > 0; off >>= 1) {
        if (tid < off) red[tid] += red[tid + off];
        __syncthreads();
    }
    float damp = 0.01f * (red[0] / (float)NELEM);

    int b = blockIdx.x;                 // 640 blocks
    int tile = b >> 6;                  // 0..9
    int li = ((b & 63) << 10) + (tid << 2);
    int bi, bj, base, nz;
    if (tile < 6) {
        int f = tile;
        bi = 1;
        while (bi * (bi + 1) / 2 <= f) ++bi;
        bj = f - bi * (bi - 1) / 2;
        base = f << 4;  nz = 16;
    } else {
        int d = tile - 6;
        bi = d; bj = d;
        base = 96 + (d << 3);  nz = 8;
    }
    const float* Pt = P + ((size_t)base << 16);
    float sx = 0.f, sy = 0.f, sz = 0.f, sw = 0.f;
    for (int zz = 0; zz < nz; ++zz) {
        float4 p4 = *(const float4*)&Pt[((size_t)zz << 16) + li];
        sx += p4.x; sy += p4.y; sz += p4.z; sw += p4.w;
    }
    int r = li >> 8, c = li & 255;
    int gi = (bi << 8) + r;
    float v4[4] = {sx, sy, sz, sw};
#pragma unroll
    for (int k = 0; k < 4; ++k) {
        int gj = (bj << 8) + c + k;
        float val = v4[k];
        if (gi == gj) val += damp;
        ushort_t h = f2bf(val), l = f2bf(val - bf2f(h));
        Hhi[gi * F + gj] = h;
        Hlo[gi * F + gj] = l;
        if (bi != bj) {
            Hhi[gj * F + gi] = h;
            Hlo[gj * F + gi] = l;
        }
    }
}

// ---------------- single matvec: y = H * ones (bf16 H) ----------------
__global__ void matvec_bf16_kernel(const ushort_t* __restrict__ Hhi, const float* __restrict__ v,
                                   float* __restrict__ y, int first) {
    __shared__ float sdata[256];
    int row = blockIdx.x, tid = threadIdx.x;
    float s = 0.f;
    if (first) {
        for (int j = tid; j < F; j += 256) s += bf2f(Hhi[row * F + j]);
    } else {
        for (int j = tid; j < F; j += 256) s = fmaf(bf2f(Hhi[row * F + j]), v[j], s);
    }
    sdata[tid] = s;
    __syncthreads();
    for (int off = 128; off > 0; off >>= 1) {
        if (tid < off) sdata[tid] += sdata[tid + off];
        __syncthreads();
    }
    if (tid == 0) y[row] = sdata[0];
}

// ---------------- initX1: lam = ||y||/32, c = 1/(1.15 lam), X1 = 2cI - c^2 H ----------------
__global__ void initX1_kernel(const ushort_t* __restrict__ Hhi, const ushort_t* __restrict__ Hlo,
                              ushort_t* __restrict__ Xhi, ushort_t* __restrict__ Xlo,
                              const float* __restrict__ y, float* __restrict__ scal) {
    __shared__ float red[256];
    int tid = threadIdx.x;
    float4 a = ((const float4*)y)[tid];
    float s = a.x * a.x + a.y * a.y + a.z * a.z + a.w * a.w;
    red[tid] = s;
    __syncthreads();
    for (int off = 128; off > 0; off >>= 1) {
        if (tid < off) red[tid] += red[tid + off];
        __syncthreads();
    }
    float lam = sqrtf(red[0]) * (1.0f / 32.0f);
    float c = 1.0f / (1.15f * lam);
    if (blockIdx.x == 0 && tid == 0) { scal[2] = lam; scal[3] = c; }
    float c2 = c * c;
    int idx0 = (blockIdx.x * 256 + tid) * 4;
#pragma unroll
    for (int k = 0; k < 4; ++k) {
        int idx = idx0 + k;
        float hv = bf2f(Hhi[idx]) + bf2f(Hlo[idx]);
        float val = -c2 * hv + (((idx >> 10) == (idx & 1023)) ? 2.f * c : 0.f);
        ushort_t h = f2bf(val);
        Xhi[idx] = h;
        Xlo[idx] = f2bf(val - bf2f(h));
    }
}

// ---------------- NS GEMM: 64x64 tile, K=1024, ring-4 prefetch-2 (measured body) ----------------
__device__ __forceinline__ void stage64(const ushort_t* __restrict__ gp, int row0, int kk,
                                        ushort_t* sbase, int tid) {
    int r = tid >> 2, pos = tid & 3;
    int kc = (pos ^ ((r >> 1) & 3)) << 3;
    gload16(gp + (size_t)(row0 + r) * 1024 + kk + kc, sbase + (size_t)(tid >> 6 << 9));
}

template <int TERMS, int MODE>
__global__ __launch_bounds__(256) void ns_gemm_kernel(
    const ushort_t* __restrict__ Ahi, const ushort_t* __restrict__ Alo,
    const ushort_t* __restrict__ Bhi, const ushort_t* __restrict__ Blo,
    const ushort_t* __restrict__ Xchi, const ushort_t* __restrict__ Xclo,
    ushort_t* __restrict__ Ohi, ushort_t* __restrict__ Olo,
    float* __restrict__ Of)
{
    constexpr int SLOT = (TERMS == 3) ? 8192 : 4096;
    __shared__ ushort_t smem[4 * SLOT];
    int tid = threadIdx.x, lane = tid & 63, w = tid >> 6;
    int wm = w >> 1, wn = w & 1;
    int row0 = blockIdx.y * 64, col0 = blockIdx.x * 64;
    int lr = lane & 15, cg = lane >> 4;

    f32x4 zero4 = {0.f, 0.f, 0.f, 0.f};
    f32x4 acc[2][2];
#pragma unroll
    for (int a = 0; a < 2; ++a)
#pragma unroll
        for (int b = 0; b < 2; ++b) acc[a][b] = zero4;

#define NS_STAGE(KT)                                                               \
    {                                                                              \
        ushort_t* sb = smem + (size_t)((KT) & 3) * SLOT;                           \
        int kk = (KT) << 5;                                                        \
        stage64(Ahi, row0, kk, sb + 0, tid);                                       \
        stage64(Bhi, col0, kk, sb + 2048, tid);                                    \
        if constexpr (TERMS == 3) {                                                \
            stage64(Alo, row0, kk, sb + 4096, tid);                                \
            stage64(Blo, col0, kk, sb + 6144, tid);                                \
        }                                                                          \
    }

#define NS_COMPUTE(KT)                                                             \
    {                                                                              \
        const ushort_t* sb = smem + (size_t)((KT) & 3) * SLOT;                     \
        bf16x8 ah[2], bh[2], al[2], bl[2];                                         \
        _Pragma("unroll")                                                          \
        for (int fx = 0; fx < 2; ++fx) {                                           \
            int xo = (cg ^ ((lr >> 1) & 3)) << 3;                                  \
            int ao = ((wm << 5) + (fx << 4) + lr) * 32 + xo;                       \
            int bo = ((wn << 5) + (fx << 4) + lr) * 32 + xo;                       \
            ah[fx] = *(const bf16x8*)&sb[0 + ao];                                  \
            bh[fx] = *(const bf16x8*)&sb[2048 + bo];                               \
            if constexpr (TERMS == 3) {                                            \
                al[fx] = *(const bf16x8*)&sb[4096 + ao];                           \
                bl[fx] = *(const bf16x8*)&sb[6144 + bo];                           \
            }                                                                      \
        }                                                                          \
        _Pragma("unroll")                                                          \
        for (int fm = 0; fm < 2; ++fm)                                             \
            _Pragma("unroll")                                                      \
            for (int fn = 0; fn < 2; ++fn) {                                       \
                acc[fm][fn] = __builtin_amdgcn_mfma_f32_16x16x32_bf16(             \
                    ah[fm], bh[fn], acc[fm][fn], 0, 0, 0);                         \
                if constexpr (TERMS == 3) {                                        \
                    acc[fm][fn] = __builtin_amdgcn_mfma_f32_16x16x32_bf16(         \
                        ah[fm], bl[fn], acc[fm][fn], 0, 0, 0);                     \
                    acc[fm][fn] = __builtin_amdgcn_mfma_f32_16x16x32_bf16(         \
                        al[fm], bh[fn], acc[fm][fn], 0, 0, 0);                     \
                }                                                                  \
            }                                                                      \
    }

    NS_STAGE(0)
    NS_STAGE(1)
    for (int kt = 0; kt < 30; ++kt) {
        NS_STAGE(kt + 2)
        if constexpr (TERMS == 3) { asm volatile("s_waitcnt vmcnt(8)" ::: "memory"); }
        else                      { asm volatile("s_waitcnt vmcnt(4)" ::: "memory"); }
        __builtin_amdgcn_s_barrier();
        __builtin_amdgcn_sched_barrier(0);
        NS_COMPUTE(kt)
        __builtin_amdgcn_sched_barrier(0);
    }
    if constexpr (TERMS == 3) { asm volatile("s_waitcnt vmcnt(4)" ::: "memory"); }
    else                      { asm volatile("s_waitcnt vmcnt(2)" ::: "memory"); }
    __builtin_amdgcn_s_barrier();
    __builtin_amdgcn_sched_barrier(0);
    NS_COMPUTE(30)
    asm volatile("s_waitcnt vmcnt(0)" ::: "memory");
    __builtin_amdgcn_s_barrier();
    __builtin_amdgcn_sched_barrier(0);
    NS_COMPUTE(31)

#pragma unroll
    for (int fm = 0; fm < 2; ++fm)
#pragma unroll
        for (int fn = 0; fn < 2; ++fn)
#pragma unroll
            for (int rr = 0; rr < 4; ++rr) {
                int r = row0 + (wm << 5) + fm * 16 + cg * 4 + rr;
                int c = col0 + (wn << 5) + fn * 16 + lr;
                size_t idx = (size_t)r * F + c;
                float val = acc[fm][fn][rr];
                if constexpr (MODE == 0) {
                    ushort_t h = f2bf(val);
                    Ohi[idx] = h;
                    Olo[idx] = f2bf(val - bf2f(h));
                } else {
                    float xc = bf2f(Xchi[idx]) + bf2f(Xclo[idx]);
                    val = 2.0f * xc - val;
                    if constexpr (MODE == 1) {
                        ushort_t h = f2bf(val);
                        Ohi[idx] = h;
                        Olo[idx] = f2bf(val - bf2f(h));
                    } else {
                        Of[idx] = val;
                    }
                }
            }
    if constexpr (MODE == 2) {
        if (blockIdx.x == 0 && blockIdx.y == 0) {
            int i0 = tid * 4;
#pragma unroll
            for (int k = 0; k < 4; ++k)
                Of[(size_t)F * F + i0 + k] = (float)(i0 + k);
        }
    }
}

// ======================= fp32 ultra-fallback =======================
__global__ void sumsq_partial_kernel(const float* __restrict__ x, float* __restrict__ partial) {
    __shared__ float sdata[256];
    int tid = threadIdx.x;
    int base = blockIdx.x * 4096;
    float s = 0.f;
    for (int i = tid; i < 4096; i += 256) {
        float v = x[base + i];
        s = fmaf(v, v, s);
    }
    sdata[tid] = s;
    __syncthreads();
    for (int off = 128; off > 0; off >>= 1) {
        if (tid < off) sdata[tid] += sdata[tid + off];
        __syncthreads();
    }
    if (tid == 0) partial[blockIdx.x] = sdata[0];
}

__global__ void finish_damp_kernel(const float* __restrict__ partial, float* __restrict__ scal) {
    __shared__ float sdata[256];
    int tid = threadIdx.x;
    float s = 0.f;
    for (int i = tid; i < 2048; i += 256) s += partial[i];
    sdata[tid] = s;
    __syncthreads();
    for (int off = 128; off > 0; off >>= 1) {
        if (tid < off) sdata[tid] += sdata[tid + off];
        __syncthreads();
    }
    if (tid == 0) {
        float mean = sdata[0] / (float)NELEM;
        scal[1] = 0.01f * mean;
    }
}

__global__ void init_v_kernel(float* __restrict__ v) {
    int i = blockIdx.x * 256 + threadIdx.x;
    if (i < F) v[i] = 1.0f;
}

__global__ void matvec_kernel(const float* __restrict__ H, const float* __restrict__ v,
                              float* __restrict__ y) {
    __shared__ float sdata[256];
    int row = blockIdx.x, tid = threadIdx.x;
    float s = 0.f;
    for (int j = tid; j < F; j += 256) s = fmaf(H[row * F + j], v[j], s);
    sdata[tid] = s;
    __syncthreads();
    for (int off = 128; off > 0; off >>= 1) {
        if (tid < off) sdata[tid] += sdata[tid + off];
        __syncthreads();
    }
    if (tid == 0) y[row] = sdata[0];
}

__global__ void normalize_kernel(const float* __restrict__ y, float* __restrict__ v,
                                 float* __restrict__ scal) {
    __shared__ float sdata[256];
    __shared__ float lam;
    int tid = threadIdx.x;
    float s = 0.f;
    for (int i = tid; i < F; i += 256) {
        float t = y[i];
        s = fmaf(t, t, s);
    }
    sdata[tid] = s;
    __syncthreads();
    for (int off = 128; off > 0; off >>= 1) {
        if (tid < off) sdata[tid] += sdata[tid + off];
        __syncthreads();
    }
    if (tid == 0) {
        lam = sqrtf(sdata[0]);
        scal[2] = lam;
        scal[3] = 1.0f / (1.05f * lam);
    }
    __syncthreads();
    float il = 1.0f / lam;
    for (int i = tid; i < F; i += 256) v[i] = y[i] * il;
}

__global__ __launch_bounds__(256) void syrk_kernel(const float* __restrict__ X,
                                                   float* __restrict__ H,
                                                   const float* __restrict__ scal) {
    __shared__ float LA[16][64];
    __shared__ float LB[16][64];
    int tx = threadIdx.x, ty = threadIdx.y;
    int t = ty * 16 + tx;
    int i0 = blockIdx.y * 64, j0 = blockIdx.x * 64;
    int lk = t >> 4;
    int lc = (t & 15) << 2;
    float acc[4][4] = {};
    for (int k0 = 0; k0 < NROWS; k0 += 16) {
        int r = (k0 + lk) * F;
        float4 a4 = *(const float4*)&X[r + i0 + lc];
        float4 b4 = *(const float4*)&X[r + j0 + lc];
        __syncthreads();
        *(float4*)&LA[lk][lc] = a4;
        *(float4*)&LB[lk][lc] = b4;
        __syncthreads();
#pragma unroll
        for (int kk = 0; kk < 16; ++kk) {
            float4 a = *(const float4*)&LA[kk][ty << 2];
            float4 b = *(const float4*)&LB[kk][tx << 2];
            float av[4] = {a.x, a.y, a.z, a.w};
            float bv[4] = {b.x, b.y, b.z, b.w};
#pragma unroll
            for (int rr = 0; rr < 4; ++rr)
#pragma unroll
                for (int cc = 0; cc < 4; ++cc)
                    acc[rr][cc] = fmaf(av[rr], bv[cc], acc[rr][cc]);
        }
    }
    float damp = scal[1];
#pragma unroll
    for (int rr = 0; rr < 4; ++rr) {
        int i = i0 + (ty << 2) + rr;
#pragma unroll
        for (int cc = 0; cc < 4; ++cc) {
            int j = j0 + (tx << 2) + cc;
            float v = acc[rr][cc];
            if (i == j) v += damp;
            H[i * F + j] = v;
        }
    }
}

__global__ void init_X_kernel(float* __restrict__ A, const float* __restrict__ scal) {
    int idx = blockIdx.x * 256 + threadIdx.x;
    int i = idx >> 10, j = idx & (F - 1);
    A[idx] = (i == j) ? scal[3] : 0.0f;
}

__global__ __launch_bounds__(256) void gemm_nn_kernel(const float* __restrict__ A,
                                                      const float* __restrict__ Bm,
                                                      float* __restrict__ C,
                                                      const float* __restrict__ D,
                                                      int mode) {
    __shared__ float LA[16][64];
    __shared__ float LB[16][64];
    int tx = threadIdx.x, ty = threadIdx.y;
    int t = ty * 16 + tx;
    int i0 = blockIdx.y * 64, j0 = blockIdx.x * 64;
    int aii = t >> 2;
    int akq = (t & 3) << 2;
    int bkk = t >> 4;
    int bjq = (t & 15) << 2;
    float acc[4][4] = {};
    for (int k0 = 0; k0 < F; k0 += 16) {
        float4 a4 = *(const float4*)&A[(i0 + aii) * F + k0 + akq];
        float4 b4 = *(const float4*)&Bm[(k0 + bkk) * F + j0 + bjq];
        __syncthreads();
        LA[akq + 0][aii] = a4.x;
        LA[akq + 1][aii] = a4.y;
        LA[akq + 2][aii] = a4.z;
        LA[akq + 3][aii] = a4.w;
        *(float4*)&LB[bkk][bjq] = b4;
        __syncthreads();
#pragma unroll
        for (int kk = 0; kk < 16; ++kk) {
            float4 a = *(const float4*)&LA[kk][ty << 2];
            float4 b = *(const float4*)&LB[kk][tx << 2];
            float av[4] = {a.x, a.y, a.z, a.w};
            float bv[4] = {b.x, b.y, b.z, b.w};
#pragma unroll
            for (int rr = 0; rr < 4; ++rr)
#pragma unroll
                for (int cc = 0; cc < 4; ++cc)
                    acc[rr][cc] = fmaf(av[rr], bv[cc], acc[rr][cc]);
        }
    }
#pragma unroll
    for (int rr = 0; rr < 4; ++rr) {
        int i = i0 + (ty << 2) + rr;
#pragma unroll
        for (int cc = 0; cc < 4; ++cc) {
            int j = j0 + (tx << 2) + cc;
            float v = acc[rr][cc];
            if (mode == 1) v = 2.0f * D[i * F + j] - v;
            C[i * F + j] = v;
        }
    }
}

__global__ void finalize_kernel(const float* __restrict__ A, float* __restrict__ out) {
    int idx = blockIdx.x * 256 + threadIdx.x;
    if (idx < F * F) out[idx] = A[idx];
    else if (idx < F * F + F) out[idx] = (float)(idx - F * F);
}

// ======================= launch =======================
extern "C" void kernel_launch(void* const* d_in, const int* in_sizes, int n_in,
                              void* d_out, int out_size, void* d_ws, size_t ws_size,
                              hipStream_t stream) {
    const float* x = (const float*)d_in[0];
    float* out = (float*)d_out;

    char* base = (char*)d_ws;
    size_t off = 0;
    auto alloc = [&](size_t bytes) -> char* {
        char* p = base + off;
        off += bytes;
        off = (off + 255) & ~(size_t)255;
        return p;
    };
    float*    scal = (float*)alloc(64 * 4);
    float*    part = (float*)alloc(2048 * 4);
    ushort_t* XThi = (ushort_t*)alloc((size_t)NELEM * 2);
    ushort_t* XTlo = (ushort_t*)alloc((size_t)NELEM * 2);
    ushort_t* Hhi  = (ushort_t*)alloc((size_t)F * F * 2);
    ushort_t* Hlo  = (ushort_t*)alloc((size_t)F * F * 2);
    ushort_t* X0hi = (ushort_t*)alloc((size_t)F * F * 2);
    ushort_t* X0lo = (ushort_t*)alloc((size_t)F * F * 2);
    ushort_t* X1hi = (ushort_t*)alloc((size_t)F * F * 2);
    ushort_t* X1lo = (ushort_t*)alloc((size_t)F * F * 2);
    ushort_t* Shi  = (ushort_t*)alloc((size_t)F * F * 2);
    ushort_t* Slo  = (ushort_t*)alloc((size_t)F * F * 2);
    float*    v    = (float*)alloc(F * 4);
    float*    y    = (float*)alloc(F * 4);
    float*    P    = (float*)alloc((size_t)128 * 65536 * 4);   // 32 MB
    size_t need = off;

    if (ws_size >= need) {
        // ======== MFMA path ========
        tconv_kernel<<<dim3(16, 128), 256, 0, stream>>>(x, XThi, XTlo, part);

        syrk256_kernel<<<128, 512, 0, stream>>>(XThi, XTlo, P);
        reduceH_kernel<<<640, 256, 0, stream>>>(P, part, Hhi, Hlo);

        matvec_bf16_kernel<<<F, 256, 0, stream>>>(Hhi, v, y, 1);
        initX1_kernel<<<1024, 256, 0, stream>>>(Hhi, Hlo, X0hi, X0lo, y, scal);

        ushort_t* xch = X0hi; ushort_t* xcl = X0lo;
        ushort_t* xnh = X1hi; ushort_t* xnl = X1lo;
        dim3 g(16, 16);
        for (int it = 0; it < 4; ++it) {
            bool last = (it == 3);
            if (it < 1) {
                ns_gemm_kernel<1, 0><<<g, 256, 0, stream>>>(xch, xcl, Hhi, Hlo,
                                                            nullptr, nullptr, Shi, Slo, nullptr);
                ns_gemm_kernel<1, 1><<<g, 256, 0, stream>>>(Shi, Slo, xch, xcl,
                                                            xch, xcl, xnh, xnl, nullptr);
            } else {
                ns_gemm_kernel<3, 0><<<g, 256, 0, stream>>>(xch, xcl, Hhi, Hlo,
                                                            nullptr, nullptr, Shi, Slo, nullptr);
                if (last)
                    ns_gemm_kernel<3, 2><<<g, 256, 0, stream>>>(Shi, Slo, xch, xcl,
                                                                xch, xcl, nullptr, nullptr, out);
                else
                    ns_gemm_kernel<3, 1><<<g, 256, 0, stream>>>(Shi, Slo, xch, xcl,
                                                                xch, xcl, xnh, xnl, nullptr);
            }
            ushort_t* th = xch; xch = xnh; xnh = th;
            ushort_t* tl = xcl; xcl = xnl; xnl = tl;
        }
    } else {
        // -------- fp32 ultra-fallback --------
        float* ws = (float*)d_ws;
        float* fscal    = ws;
        float* fpartial = ws + 64;
        float* fH  = ws + 4096;
        float* fA  = fH + F * F;
        float* fB  = fA + F * F;
        float* fv  = fB + F * F;
        float* fy  = fv + F;
        float* R = out;

        sumsq_partial_kernel<<<2048, 256, 0, stream>>>(x, fpartial);
        finish_damp_kernel<<<1, 256, 0, stream>>>(fpartial, fscal);

        dim3 grid16(16, 16), blk16(16, 16);
        syrk_kernel<<<grid16, blk16, 0, stream>>>(x, fH, fscal);

        init_v_kernel<<<4, 256, 0, stream>>>(fv);
        for (int it = 0; it < 12; ++it) {
            matvec_kernel<<<F, 256, 0, stream>>>(fH, fv, fy);
            normalize_kernel<<<1, 256, 0, stream>>>(fy, fv, fscal);
        }

        init_X_kernel<<<(F * F) / 256, 256, 0, stream>>>(fA, fscal);
        float* Xc = fA;
        float* Xn = fB;
        for (int it = 0; it < 8; ++it) {
            gemm_nn_kernel<<<grid16, blk16, 0, stream>>>(fH, Xc, R, nullptr, 0);
            gemm_nn_kernel<<<grid16, blk16, 0, stream>>>(Xc, R, Xn, Xc, 1);
            float* tmp = Xc; Xc = Xn; Xn = tmp;
        }

        finalize_kernel<<<(F * F + F + 255) / 256, 256, 0, stream>>>(Xc, out);
    }
}

// Round 11
// 154.859 us; speedup vs baseline: 3.0875x; 2.2909x over previous
//
#include <hip/hip_runtime.h>
#include <math.h>

#define F 1024
#define NROWS 8192
#define NELEM (NROWS * F)

typedef unsigned short ushort_t;
typedef short bf16x8 __attribute__((ext_vector_type(8)));
typedef float f32x4 __attribute__((ext_vector_type(4)));
typedef unsigned short ushort8 __attribute__((ext_vector_type(8)));

__device__ __forceinline__ ushort_t f2bf(float f) {
  unsigned u = __float_as_uint(f);
  unsigned r = (u + 0x7fffu + ((u >> 16) & 1u)) >> 16;
  return (ushort_t)r;
}
__device__ __forceinline__ float bf2f(ushort_t b) {
  return __uint_as_float(((unsigned)b) << 16);
}

typedef const __attribute__((address_space(1))) unsigned int* gas_ptr;
typedef __attribute__((address_space(3))) unsigned int* las_ptr;
__device__ __forceinline__ void gload16(const void* g, const void* l) {
  __builtin_amdgcn_global_load_lds((gas_ptr)(unsigned long long)g,
                                   (las_ptr)(unsigned int)(unsigned long long)l,
                                   16, 0, 0);
}

// ---------------- tconv + fused sumsq ----------------
__global__ __launch_bounds__(256) void tconv_kernel(const float* __restrict__ x,
                                                    ushort_t* __restrict__ xthi,
                                                    ushort_t* __restrict__ xtlo,
                                                    float* __restrict__ partial) {
    __shared__ ushort_t th[64][68];
    __shared__ ushort_t tl[64][68];
    __shared__ float sdata[256];
    int c0 = blockIdx.x * 64;
    int r0 = blockIdx.y * 64;
    int tid = threadIdx.x;
    float ss = 0.f;
#pragma unroll
    for (int i = 0; i < 4; ++i) {
        int q = tid + 256 * i;
        int r = q >> 4;
        int cq = (q & 15) << 2;
        float4 vx = *(const float4*)&x[(size_t)(r0 + r) * 1024 + c0 + cq];
        float vv[4] = {vx.x, vx.y, vx.z, vx.w};
#pragma unroll
        for (int j = 0; j < 4; ++j) {
            ss = fmaf(vv[j], vv[j], ss);
            ushort_t h = f2bf(vv[j]);
            ushort_t l = f2bf(vv[j] - bf2f(h));
            th[r][cq + j] = h;
            tl[r][cq + j] = l;
        }
    }
    sdata[tid] = ss;
    __syncthreads();
    for (int off = 128; off > 0; off >>= 1) {
        if (tid < off) sdata[tid] += sdata[tid + off];
        __syncthreads();
    }
    if (tid == 0) partial[blockIdx.y * 16 + blockIdx.x] = sdata[0];
#pragma unroll
    for (int i = 0; i < 2; ++i) {
        int q = tid + 256 * i;
        int c = q >> 3;
        int rq = (q & 7) << 3;
        ushort8 oh, ol;
#pragma unroll
        for (int j = 0; j < 8; ++j) {
            oh[j] = th[rq + j][c];
            ol[j] = tl[rq + j][c];
        }
        *(ushort8*)&xthi[(size_t)(c0 + c) * 8192 + r0 + rq] = oh;
        *(ushort8*)&xtlo[(size_t)(c0 + c) * 8192 + r0 + rq] = ol;
    }
}

// ---------------- SYRK: triangle + z8, dbuf 64KB, diag half-staging (R7-verified) ----------------
__device__ __forceinline__ void stage128(const ushort_t* __restrict__ gp, int row0, int kk,
                                         ushort_t* sbase, int w, int lane) {
#pragma unroll
    for (int half = 0; half < 2; ++half) {
        int s = half * 256 + (w << 6) + lane;
        int r = s >> 2, pos = s & 3;
        int kc = (pos ^ ((r >> 1) & 3)) << 3;
        gload16(gp + (size_t)(row0 + r) * 8192 + kk + kc,
                sbase + (size_t)((half << 8) + (w << 6)) * 8);
    }
}

__global__ __launch_bounds__(256, 2) void syrk_mfma_kernel(
    const ushort_t* __restrict__ XThi, const ushort_t* __restrict__ XTlo,
    float* __restrict__ P)
{
    __shared__ ushort_t smem[2][16384]; // per buf: Ahi@0 Alo@4096 Bhi@8192 Blo@12288
    int id = blockIdx.x;
    int z = id & 7, t = id >> 3;
    int bi = 0;
    while ((bi + 1) * (bi + 2) / 2 <= t) ++bi;
    int bj = t - bi * (bi + 1) / 2;
    int arow0 = bi * 128, brow0 = bj * 128;
    int k0 = z * 1024;

    int tid = threadIdx.x, lane = tid & 63, w = tid >> 6;
    int wm = w >> 1, wn = w & 1;
    int lr = lane & 15, cg = lane >> 4;

    f32x4 zero4 = {0.f, 0.f, 0.f, 0.f};
    f32x4 acc[4][4];
#pragma unroll
    for (int a = 0; a < 4; ++a)
#pragma unroll
        for (int b = 0; b < 4; ++b) acc[a][b] = zero4;

#define SY_STAGE_F(BUF, KT)                                                        \
    {                                                                              \
        ushort_t* sb = smem[BUF];                                                  \
        int kk = k0 + ((KT) << 5);                                                 \
        stage128(XThi, arow0, kk, sb + 0, w, lane);                                \
        stage128(XTlo, arow0, kk, sb + 4096, w, lane);                             \
        stage128(XThi, brow0, kk, sb + 8192, w, lane);                             \
        stage128(XTlo, brow0, kk, sb + 12288, w, lane);                            \
    }

#define SY_STAGE_D(BUF, KT)                                                        \
    {                                                                              \
        ushort_t* sb = smem[BUF];                                                  \
        int kk = k0 + ((KT) << 5);                                                 \
        stage128(XThi, arow0, kk, sb + 0, w, lane);                                \
        stage128(XTlo, arow0, kk, sb + 4096, w, lane);                             \
    }

#define SY_COMP(BUF, BH, BL)                                                       \
    {                                                                              \
        const ushort_t* sb = smem[BUF];                                            \
        bf16x8 ah[4], bh[4], al[4], bl[4];                                         \
        _Pragma("unroll")                                                          \
        for (int fx = 0; fx < 4; ++fx) {                                           \
            int xo = (cg ^ ((lr >> 1) & 3)) << 3;                                  \
            int ao = ((wm << 6) + (fx << 4) + lr) * 32 + xo;                       \
            int bo = ((wn << 6) + (fx << 4) + lr) * 32 + xo;                       \
            ah[fx] = *(const bf16x8*)&sb[0 + ao];                                  \
            al[fx] = *(const bf16x8*)&sb[4096 + ao];                               \
            bh[fx] = *(const bf16x8*)&sb[(BH) + bo];                               \
            bl[fx] = *(const bf16x8*)&sb[(BL) + bo];                               \
        }                                                                          \
        _Pragma("unroll")                                                          \
        for (int fm = 0; fm < 4; ++fm)                                             \
            _Pragma("unroll")                                                      \
            for (int fn = 0; fn < 4; ++fn) {                                       \
                acc[fm][fn] = __builtin_amdgcn_mfma_f32_16x16x32_bf16(             \
                    ah[fm], bh[fn], acc[fm][fn], 0, 0, 0);                         \
                acc[fm][fn] = __builtin_amdgcn_mfma_f32_16x16x32_bf16(             \
                    ah[fm], bl[fn], acc[fm][fn], 0, 0, 0);                         \
                acc[fm][fn] = __builtin_amdgcn_mfma_f32_16x16x32_bf16(             \
                    al[fm], bh[fn], acc[fm][fn], 0, 0, 0);                         \
            }                                                                      \
    }

    if (bi != bj) {
        SY_STAGE_F(0, 0)
        for (int kt = 0; kt < 31; ++kt) {
            int buf = kt & 1;
            if (buf == 0) SY_STAGE_F(1, kt + 1) else SY_STAGE_F(0, kt + 1)
            asm volatile("s_waitcnt vmcnt(8)" ::: "memory");
            __builtin_amdgcn_s_barrier();
            __builtin_amdgcn_sched_barrier(0);
            if (buf == 0) SY_COMP(0, 8192, 12288) else SY_COMP(1, 8192, 12288)
            __builtin_amdgcn_sched_barrier(0);
            __builtin_amdgcn_s_barrier();
        }
        asm volatile("s_waitcnt vmcnt(0)" ::: "memory");
        __builtin_amdgcn_s_barrier();
        __builtin_amdgcn_sched_barrier(0);
        SY_COMP(1, 8192, 12288)
    } else {
        SY_STAGE_D(0, 0)
        for (int kt = 0; kt < 31; ++kt) {
            int buf = kt & 1;
            if (buf == 0) SY_STAGE_D(1, kt + 1) else SY_STAGE_D(0, kt + 1)
            asm volatile("s_waitcnt vmcnt(4)" ::: "memory");
            __builtin_amdgcn_s_barrier();
            __builtin_amdgcn_sched_barrier(0);
            if (buf == 0) SY_COMP(0, 0, 4096) else SY_COMP(1, 0, 4096)
            __builtin_amdgcn_sched_barrier(0);
            __builtin_amdgcn_s_barrier();
        }
        asm volatile("s_waitcnt vmcnt(0)" ::: "memory");
        __builtin_amdgcn_s_barrier();
        __builtin_amdgcn_sched_barrier(0);
        SY_COMP(1, 0, 4096)
    }

    float* Pt = P + ((size_t)(t * 8 + z) << 14);
#pragma unroll
    for (int fm = 0; fm < 4; ++fm)
#pragma unroll
        for (int fn = 0; fn < 4; ++fn)
#pragma unroll
            for (int rr = 0; rr < 4; ++rr) {
                int row = (wm << 6) + fm * 16 + cg * 4 + rr;
                int col = (wn << 6) + fn * 16 + lr;
                Pt[row * 128 + col] = acc[fm][fn][rr];
            }
}

// ---------------- reduceH: fused damp-reduce + z8 sum + split + mirror ----------------
__global__ void reduceH_kernel(const float* __restrict__ P, const float* __restrict__ part,
                               ushort_t* __restrict__ Hhi, ushort_t* __restrict__ Hlo) {
    __shared__ float red[256];
    int tid = threadIdx.x;
    float s0 = 0.f;
    for (int i = tid; i < 2048; i += 256) s0 += part[i];
    red[tid] = s0;
    __syncthreads();
    for (int off = 128; off > 0; off >>= 1) {
        if (tid < off) red[tid] += red[tid + off];
        __syncthreads();
    }
    float damp = 0.01f * (red[0] / (float)NELEM);

    int b = blockIdx.x;
    int tile = b >> 6;
    int li = ((b & 63) << 8) + tid;
    int bi = 0;
    while ((bi + 1) * (bi + 2) / 2 <= tile) ++bi;
    int bj = tile - bi * (bi + 1) / 2;
    const float* Pt = P + ((size_t)tile << 17);
    float s = 0.f;
#pragma unroll
    for (int z = 0; z < 8; ++z) s += Pt[((size_t)z << 14) + li];
    int r = li >> 7, c = li & 127;
    int gi = bi * 128 + r, gj = bj * 128 + c;
    if (gi == gj) s += damp;
    ushort_t h = f2bf(s), l = f2bf(s - bf2f(h));
    Hhi[gi * F + gj] = h;
    Hlo[gi * F + gj] = l;
    if (bi != bj) {
        Hhi[gj * F + gi] = h;
        Hlo[gj * F + gi] = l;
    }
}

// ---------------- single matvec: y = H * ones (bf16 H) ----------------
__global__ void matvec_bf16_kernel(const ushort_t* __restrict__ Hhi, const float* __restrict__ v,
                                   float* __restrict__ y, int first) {
    __shared__ float sdata[256];
    int row = blockIdx.x, tid = threadIdx.x;
    float s = 0.f;
    if (first) {
        for (int j = tid; j < F; j += 256) s += bf2f(Hhi[row * F + j]);
    } else {
        for (int j = tid; j < F; j += 256) s = fmaf(bf2f(Hhi[row * F + j]), v[j], s);
    }
    sdata[tid] = s;
    __syncthreads();
    for (int off = 128; off > 0; off >>= 1) {
        if (tid < off) sdata[tid] += sdata[tid + off];
        __syncthreads();
    }
    if (tid == 0) y[row] = sdata[0];
}

// ---------------- initX1: lam = ||y||/32 (per-block), c = 1/(1.15 lam), X1 = 2cI - c^2 H ----------------
__global__ void initX1_kernel(const ushort_t* __restrict__ Hhi, const ushort_t* __restrict__ Hlo,
                              ushort_t* __restrict__ Xhi, ushort_t* __restrict__ Xlo,
                              const float* __restrict__ y, float* __restrict__ scal) {
    __shared__ float red[256];
    int tid = threadIdx.x;
    float4 a = ((const float4*)y)[tid];
    float s = a.x * a.x + a.y * a.y + a.z * a.z + a.w * a.w;
    red[tid] = s;
    __syncthreads();
    for (int off = 128; off > 0; off >>= 1) {
        if (tid < off) red[tid] += red[tid + off];
        __syncthreads();
    }
    float lam = sqrtf(red[0]) * (1.0f / 32.0f);   // ||H*1|| / ||1||
    float c = 1.0f / (1.15f * lam);
    if (blockIdx.x == 0 && tid == 0) { scal[2] = lam; scal[3] = c; }
    float c2 = c * c;
    int idx0 = (blockIdx.x * 256 + tid) * 4;
#pragma unroll
    for (int k = 0; k < 4; ++k) {
        int idx = idx0 + k;
        float hv = bf2f(Hhi[idx]) + bf2f(Hlo[idx]);
        float val = -c2 * hv + (((idx >> 10) == (idx & 1023)) ? 2.f * c : 0.f);
        ushort_t h = f2bf(val);
        Xhi[idx] = h;
        Xlo[idx] = f2bf(val - bf2f(h));
    }
}

// ---------------- NS GEMM: 64x64 tile, K=1024, ring-4 prefetch-2 (R7-verified body) ----------------
__device__ __forceinline__ void stage64(const ushort_t* __restrict__ gp, int row0, int kk,
                                        ushort_t* sbase, int tid) {
    int r = tid >> 2, pos = tid & 3;
    int kc = (pos ^ ((r >> 1) & 3)) << 3;
    gload16(gp + (size_t)(row0 + r) * 1024 + kk + kc, sbase + (size_t)(tid >> 6 << 9));
}

template <int TERMS, int MODE>
__global__ __launch_bounds__(256) void ns_gemm_kernel(
    const ushort_t* __restrict__ Ahi, const ushort_t* __restrict__ Alo,
    const ushort_t* __restrict__ Bhi, const ushort_t* __restrict__ Blo,
    const ushort_t* __restrict__ Xchi, const ushort_t* __restrict__ Xclo,
    ushort_t* __restrict__ Ohi, ushort_t* __restrict__ Olo,
    float* __restrict__ Of)
{
    constexpr int SLOT = (TERMS == 3) ? 8192 : 4096;
    __shared__ ushort_t smem[4 * SLOT];
    int tid = threadIdx.x, lane = tid & 63, w = tid >> 6;
    int wm = w >> 1, wn = w & 1;
    int row0 = blockIdx.y * 64, col0 = blockIdx.x * 64;
    int lr = lane & 15, cg = lane >> 4;

    f32x4 zero4 = {0.f, 0.f, 0.f, 0.f};
    f32x4 acc[2][2];
#pragma unroll
    for (int a = 0; a < 2; ++a)
#pragma unroll
        for (int b = 0; b < 2; ++b) acc[a][b] = zero4;

#define NS_STAGE(KT)                                                               \
    {                                                                              \
        ushort_t* sb = smem + (size_t)((KT) & 3) * SLOT;                           \
        int kk = (KT) << 5;                                                        \
        stage64(Ahi, row0, kk, sb + 0, tid);                                       \
        stage64(Bhi, col0, kk, sb + 2048, tid);                                    \
        if constexpr (TERMS == 3) {                                                \
            stage64(Alo, row0, kk, sb + 4096, tid);                                \
            stage64(Blo, col0, kk, sb + 6144, tid);                                \
        }                                                                          \
    }

#define NS_COMPUTE(KT)                                                             \
    {                                                                              \
        const ushort_t* sb = smem + (size_t)((KT) & 3) * SLOT;                     \
        bf16x8 ah[2], bh[2], al[2], bl[2];                                         \
        _Pragma("unroll")                                                          \
        for (int fx = 0; fx < 2; ++fx) {                                           \
            int xo = (cg ^ ((lr >> 1) & 3)) << 3;                                  \
            int ao = ((wm << 5) + (fx << 4) + lr) * 32 + xo;                       \
            int bo = ((wn << 5) + (fx << 4) + lr) * 32 + xo;                       \
            ah[fx] = *(const bf16x8*)&sb[0 + ao];                                  \
            bh[fx] = *(const bf16x8*)&sb[2048 + bo];                               \
            if constexpr (TERMS == 3) {                                            \
                al[fx] = *(const bf16x8*)&sb[4096 + ao];                           \
                bl[fx] = *(const bf16x8*)&sb[6144 + bo];                           \
            }                                                                      \
        }                                                                          \
        _Pragma("unroll")                                                          \
        for (int fm = 0; fm < 2; ++fm)                                             \
            _Pragma("unroll")                                                      \
            for (int fn = 0; fn < 2; ++fn) {                                       \
                acc[fm][fn] = __builtin_amdgcn_mfma_f32_16x16x32_bf16(             \
                    ah[fm], bh[fn], acc[fm][fn], 0, 0, 0);                         \
                if constexpr (TERMS == 3) {                                        \
                    acc[fm][fn] = __builtin_amdgcn_mfma_f32_16x16x32_bf16(         \
                        ah[fm], bl[fn], acc[fm][fn], 0, 0, 0);                     \
                    acc[fm][fn] = __builtin_amdgcn_mfma_f32_16x16x32_bf16(         \
                        al[fm], bh[fn], acc[fm][fn], 0, 0, 0);                     \
                }                                                                  \
            }                                                                      \
    }

    NS_STAGE(0)
    NS_STAGE(1)
    for (int kt = 0; kt < 30; ++kt) {
        NS_STAGE(kt + 2)
        if constexpr (TERMS == 3) { asm volatile("s_waitcnt vmcnt(8)" ::: "memory"); }
        else                      { asm volatile("s_waitcnt vmcnt(4)" ::: "memory"); }
        __builtin_amdgcn_s_barrier();
        __builtin_amdgcn_sched_barrier(0);
        NS_COMPUTE(kt)
        __builtin_amdgcn_sched_barrier(0);
    }
    if constexpr (TERMS == 3) { asm volatile("s_waitcnt vmcnt(4)" ::: "memory"); }
    else                      { asm volatile("s_waitcnt vmcnt(2)" ::: "memory"); }
    __builtin_amdgcn_s_barrier();
    __builtin_amdgcn_sched_barrier(0);
    NS_COMPUTE(30)
    asm volatile("s_waitcnt vmcnt(0)" ::: "memory");
    __builtin_amdgcn_s_barrier();
    __builtin_amdgcn_sched_barrier(0);
    NS_COMPUTE(31)

#pragma unroll
    for (int fm = 0; fm < 2; ++fm)
#pragma unroll
        for (int fn = 0; fn < 2; ++fn)
#pragma unroll
            for (int rr = 0; rr < 4; ++rr) {
                int r = row0 + (wm << 5) + fm * 16 + cg * 4 + rr;
                int c = col0 + (wn << 5) + fn * 16 + lr;
                size_t idx = (size_t)r * F + c;
                float val = acc[fm][fn][rr];
                if constexpr (MODE == 0) {
                    ushort_t h = f2bf(val);
                    Ohi[idx] = h;
                    Olo[idx] = f2bf(val - bf2f(h));
                } else {
                    float xc = bf2f(Xchi[idx]) + bf2f(Xclo[idx]);
                    val = 2.0f * xc - val;
                    if constexpr (MODE == 1) {
                        ushort_t h = f2bf(val);
                        Ohi[idx] = h;
                        Olo[idx] = f2bf(val - bf2f(h));
                    } else {
                        Of[idx] = val;
                    }
                }
            }
    if constexpr (MODE == 2) {
        if (blockIdx.x == 0 && blockIdx.y == 0) {
            int i0 = tid * 4;
#pragma unroll
            for (int k = 0; k < 4; ++k)
                Of[(size_t)F * F + i0 + k] = (float)(i0 + k);
        }
    }
}

// ======================= fp32 ultra-fallback =======================
__global__ void sumsq_partial_kernel(const float* __restrict__ x, float* __restrict__ partial) {
    __shared__ float sdata[256];
    int tid = threadIdx.x;
    int base = blockIdx.x * 4096;
    float s = 0.f;
    for (int i = tid; i < 4096; i += 256) {
        float v = x[base + i];
        s = fmaf(v, v, s);
    }
    sdata[tid] = s;
    __syncthreads();
    for (int off = 128; off > 0; off >>= 1) {
        if (tid < off) sdata[tid] += sdata[tid + off];
        __syncthreads();
    }
    if (tid == 0) partial[blockIdx.x] = sdata[0];
}

__global__ void finish_damp_kernel(const float* __restrict__ partial, float* __restrict__ scal) {
    __shared__ float sdata[256];
    int tid = threadIdx.x;
    float s = 0.f;
    for (int i = tid; i < 2048; i += 256) s += partial[i];
    sdata[tid] = s;
    __syncthreads();
    for (int off = 128; off > 0; off >>= 1) {
        if (tid < off) sdata[tid] += sdata[tid + off];
        __syncthreads();
    }
    if (tid == 0) {
        float mean = sdata[0] / (float)NELEM;
        scal[1] = 0.01f * mean;
    }
}

__global__ void init_v_kernel(float* __restrict__ v) {
    int i = blockIdx.x * 256 + threadIdx.x;
    if (i < F) v[i] = 1.0f;
}

__global__ void matvec_kernel(const float* __restrict__ H, const float* __restrict__ v,
                              float* __restrict__ y) {
    __shared__ float sdata[256];
    int row = blockIdx.x, tid = threadIdx.x;
    float s = 0.f;
    for (int j = tid; j < F; j += 256) s = fmaf(H[row * F + j], v[j], s);
    sdata[tid] = s;
    __syncthreads();
    for (int off = 128; off > 0; off >>= 1) {
        if (tid < off) sdata[tid] += sdata[tid + off];
        __syncthreads();
    }
    if (tid == 0) y[row] = sdata[0];
}

__global__ void normalize_kernel(const float* __restrict__ y, float* __restrict__ v,
                                 float* __restrict__ scal) {
    __shared__ float sdata[256];
    __shared__ float lam;
    int tid = threadIdx.x;
    float s = 0.f;
    for (int i = tid; i < F; i += 256) {
        float t = y[i];
        s = fmaf(t, t, s);
    }
    sdata[tid] = s;
    __syncthreads();
    for (int off = 128; off > 0; off >>= 1) {
        if (tid < off) sdata[tid] += sdata[tid + off];
        __syncthreads();
    }
    if (tid == 0) {
        lam = sqrtf(sdata[0]);
        scal[2] = lam;
        scal[3] = 1.0f / (1.05f * lam);
    }
    __syncthreads();
    float il = 1.0f / lam;
    for (int i = tid; i < F; i += 256) v[i] = y[i] * il;
}

__global__ __launch_bounds__(256) void syrk_kernel(const float* __restrict__ X,
                                                   float* __restrict__ H,
                                                   const float* __restrict__ scal) {
    __shared__ float LA[16][64];
    __shared__ float LB[16][64];
    int tx = threadIdx.x, ty = threadIdx.y;
    int t = ty * 16 + tx;
    int i0 = blockIdx.y * 64, j0 = blockIdx.x * 64;
    int lk = t >> 4;
    int lc = (t & 15) << 2;
    float acc[4][4] = {};
    for (int k0 = 0; k0 < NROWS; k0 += 16) {
        int r = (k0 + lk) * F;
        float4 a4 = *(const float4*)&X[r + i0 + lc];
        float4 b4 = *(const float4*)&X[r + j0 + lc];
        __syncthreads();
        *(float4*)&LA[lk][lc] = a4;
        *(float4*)&LB[lk][lc] = b4;
        __syncthreads();
#pragma unroll
        for (int kk = 0; kk < 16; ++kk) {
            float4 a = *(const float4*)&LA[kk][ty << 2];
            float4 b = *(const float4*)&LB[kk][tx << 2];
            float av[4] = {a.x, a.y, a.z, a.w};
            float bv[4] = {b.x, b.y, b.z, b.w};
#pragma unroll
            for (int rr = 0; rr < 4; ++rr)
#pragma unroll
                for (int cc = 0; cc < 4; ++cc)
                    acc[rr][cc] = fmaf(av[rr], bv[cc], acc[rr][cc]);
        }
    }
    float damp = scal[1];
#pragma unroll
    for (int rr = 0; rr < 4; ++rr) {
        int i = i0 + (ty << 2) + rr;
#pragma unroll
        for (int cc = 0; cc < 4; ++cc) {
            int j = j0 + (tx << 2) + cc;
            float v = acc[rr][cc];
            if (i == j) v += damp;
            H[i * F + j] = v;
        }
    }
}

__global__ void init_X_kernel(float* __restrict__ A, const float* __restrict__ scal) {
    int idx = blockIdx.x * 256 + threadIdx.x;
    int i = idx >> 10, j = idx & (F - 1);
    A[idx] = (i == j) ? scal[3] : 0.0f;
}

__global__ __launch_bounds__(256) void gemm_nn_kernel(const float* __restrict__ A,
                                                      const float* __restrict__ Bm,
                                                      float* __restrict__ C,
                                                      const float* __restrict__ D,
                                                      int mode) {
    __shared__ float LA[16][64];
    __shared__ float LB[16][64];
    int tx = threadIdx.x, ty = threadIdx.y;
    int t = ty * 16 + tx;
    int i0 = blockIdx.y * 64, j0 = blockIdx.x * 64;
    int aii = t >> 2;
    int akq = (t & 3) << 2;
    int bkk = t >> 4;
    int bjq = (t & 15) << 2;
    float acc[4][4] = {};
    for (int k0 = 0; k0 < F; k0 += 16) {
        float4 a4 = *(const float4*)&A[(i0 + aii) * F + k0 + akq];
        float4 b4 = *(const float4*)&Bm[(k0 + bkk) * F + j0 + bjq];
        __syncthreads();
        LA[akq + 0][aii] = a4.x;
        LA[akq + 1][aii] = a4.y;
        LA[akq + 2][aii] = a4.z;
        LA[akq + 3][aii] = a4.w;
        *(float4*)&LB[bkk][bjq] = b4;
        __syncthreads();
#pragma unroll
        for (int kk = 0; kk < 16; ++kk) {
            float4 a = *(const float4*)&LA[kk][ty << 2];
            float4 b = *(const float4*)&LB[kk][tx << 2];
            float av[4] = {a.x, a.y, a.z, a.w};
            float bv[4] = {b.x, b.y, b.z, b.w};
#pragma unroll
            for (int rr = 0; rr < 4; ++rr)
#pragma unroll
                for (int cc = 0; cc < 4; ++cc)
                    acc[rr][cc] = fmaf(av[rr], bv[cc], acc[rr][cc]);
        }
    }
#pragma unroll
    for (int rr = 0; rr < 4; ++rr) {
        int i = i0 + (ty << 2) + rr;
#pragma unroll
        for (int cc = 0; cc < 4; ++cc) {
            int j = j0 + (tx << 2) + cc;
            float v = acc[rr][cc];
            if (mode == 1) v = 2.0f * D[i * F + j] - v;
            C[i * F + j] = v;
        }
    }
}

__global__ void finalize_kernel(const float* __restrict__ A, float* __restrict__ out) {
    int idx = blockIdx.x * 256 + threadIdx.x;
    if (idx < F * F) out[idx] = A[idx];
    else if (idx < F * F + F) out[idx] = (float)(idx - F * F);
}

// ======================= launch =======================
extern "C" void kernel_launch(void* const* d_in, const int* in_sizes, int n_in,
                              void* d_out, int out_size, void* d_ws, size_t ws_size,
                              hipStream_t stream) {
    const float* x = (const float*)d_in[0];
    float* out = (float*)d_out;

    char* base = (char*)d_ws;
    size_t off = 0;
    auto alloc = [&](size_t bytes) -> char* {
        char* p = base + off;
        off += bytes;
        off = (off + 255) & ~(size_t)255;
        return p;
    };
    float*    scal = (float*)alloc(64 * 4);
    float*    part = (float*)alloc(2048 * 4);
    ushort_t* XThi = (ushort_t*)alloc((size_t)NELEM * 2);
    ushort_t* XTlo = (ushort_t*)alloc((size_t)NELEM * 2);
    ushort_t* Hhi  = (ushort_t*)alloc((size_t)F * F * 2);
    ushort_t* Hlo  = (ushort_t*)alloc((size_t)F * F * 2);
    ushort_t* X0hi = (ushort_t*)alloc((size_t)F * F * 2);
    ushort_t* X0lo = (ushort_t*)alloc((size_t)F * F * 2);
    ushort_t* X1hi = (ushort_t*)alloc((size_t)F * F * 2);
    ushort_t* X1lo = (ushort_t*)alloc((size_t)F * F * 2);
    ushort_t* Shi  = (ushort_t*)alloc((size_t)F * F * 2);
    ushort_t* Slo  = (ushort_t*)alloc((size_t)F * F * 2);
    float*    v    = (float*)alloc(F * 4);
    float*    y    = (float*)alloc(F * 4);
    float*    P    = (float*)alloc((size_t)36 * 8 * 16384 * 4);
    size_t need = off;

    if (ws_size >= need) {
        // ======== MFMA path (13 launches, R7 structure) ========
        tconv_kernel<<<dim3(16, 128), 256, 0, stream>>>(x, XThi, XTlo, part);

        syrk_mfma_kernel<<<288, 256, 0, stream>>>(XThi, XTlo, P);
        reduceH_kernel<<<36 * 64, 256, 0, stream>>>(P, part, Hhi, Hlo);

        matvec_bf16_kernel<<<F, 256, 0, stream>>>(Hhi, v, y, 1);
        initX1_kernel<<<1024, 256, 0, stream>>>(Hhi, Hlo, X0hi, X0lo, y, scal);

        // 4 NS iterations: [t1, t1, t3, t3]; last writes fp32 out + perm
        ushort_t* xch = X0hi; ushort_t* xcl = X0lo;
        ushort_t* xnh = X1hi; ushort_t* xnl = X1lo;
        dim3 g(16, 16);
        for (int it = 0; it < 4; ++it) {
            bool last = (it == 3);
            if (it < 2) {
                ns_gemm_kernel<1, 0><<<g, 256, 0, stream>>>(xch, xcl, Hhi, Hlo,
                                                            nullptr, nullptr, Shi, Slo, nullptr);
                ns_gemm_kernel<1, 1><<<g, 256, 0, stream>>>(Shi, Slo, xch, xcl,
                                                            xch, xcl, xnh, xnl, nullptr);
            } else {
                ns_gemm_kernel<3, 0><<<g, 256, 0, stream>>>(xch, xcl, Hhi, Hlo,
                                                            nullptr, nullptr, Shi, Slo, nullptr);
                if (last)
                    ns_gemm_kernel<3, 2><<<g, 256, 0, stream>>>(Shi, Slo, xch, xcl,
                                                                xch, xcl, nullptr, nullptr, out);
                else
                    ns_gemm_kernel<3, 1><<<g, 256, 0, stream>>>(Shi, Slo, xch, xcl,
                                                                xch, xcl, xnh, xnl, nullptr);
            }
            ushort_t* th = xch; xch = xnh; xnh = th;
            ushort_t* tl = xcl; xcl = xnl; xnl = tl;
        }
    } else {
        // -------- fp32 ultra-fallback --------
        float* ws = (float*)d_ws;
        float* fscal    = ws;
        float* fpartial = ws + 64;
        float* fH  = ws + 4096;
        float* fA  = fH + F * F;
        float* fB  = fA + F * F;
        float* fv  = fB + F * F;
        float* fy  = fv + F;
        float* R = out;

        sumsq_partial_kernel<<<2048, 256, 0, stream>>>(x, fpartial);
        finish_damp_kernel<<<1, 256, 0, stream>>>(fpartial, fscal);

        dim3 grid16(16, 16), blk16(16, 16);
        syrk_kernel<<<grid16, blk16, 0, stream>>>(x, fH, fscal);

        init_v_kernel<<<4, 256, 0, stream>>>(fv);
        for (int it = 0; it < 12; ++it) {
            matvec_kernel<<<F, 256, 0, stream>>>(fH, fv, fy);
            normalize_kernel<<<1, 256, 0, stream>>>(fy, fv, fscal);
        }

        init_X_kernel<<<(F * F) / 256, 256, 0, stream>>>(fA, fscal);
        float* Xc = fA;
        float* Xn = fB;
        for (int it = 0; it < 8; ++it) {
            gemm_nn_kernel<<<grid16, blk16, 0, stream>>>(fH, Xc, R, nullptr, 0);
            gemm_nn_kernel<<<grid16, blk16, 0, stream>>>(Xc, R, Xn, Xc, 1);
            float* tmp = Xc; Xc = Xn; Xn = tmp;
        }

        finalize_kernel<<<(F * F + F + 255) / 256, 256, 0, stream>>>(Xc, out);
    }
}